// Round 7
// baseline (741.803 us; speedup 1.0000x reference)
//
#include <hip/hip_runtime.h>
#include <cstdint>

// ---------------------------------------------------------------------------
// Round 7: inputs fp32, OUTPUTS FP32 (theory: rounds 1-3 failed only because
// they wrote bf16 into a float32 d_out; rounds 4-6 crashed because bf16-
// misreading fp32 bytes made all scores NaN -> i1=-1 -> OOB atomic scatter).
// Build = exact round-3 structure (proven to run on HW) with float outputs
// + defensive clamps (i1 fallback, e/r bounds) so no input can fault.
// ---------------------------------------------------------------------------

#define T_TOK 4096
#define D_DIM 512
#define F_DIM 2048
#define E_EXP 8
#define NROWS 9216      // 8192 assignments + 8*128 pad
#define MTILES 144      // NROWS / 64

typedef unsigned short u16;

__device__ __forceinline__ u16 f2b(float f) {
    return __builtin_bit_cast(unsigned short, (__bf16)f);
}
__device__ __forceinline__ float b2f(u16 v) {
    unsigned int u = ((unsigned int)v) << 16;
    return __builtin_bit_cast(float, u);
}

// ---------------- anchors: a_n = a / max(||a||, eps) ------------------------
__global__ void anchors_k(const float* __restrict__ anchors,
                          float* __restrict__ an, float* __restrict__ dout_an) {
    int tid = threadIdx.x;           // 512 threads = 8 waves, wave e = anchor e
    int lane = tid & 63, e = tid >> 6;
    const float4* ar = (const float4*)(anchors + e * D_DIM + lane * 8);
    float4 v0 = ar[0], v1 = ar[1];
    float ss = v0.x*v0.x + v0.y*v0.y + v0.z*v0.z + v0.w*v0.w
             + v1.x*v1.x + v1.y*v1.y + v1.z*v1.z + v1.w*v1.w;
#pragma unroll
    for (int off = 32; off >= 1; off >>= 1) ss += __shfl_xor(ss, off, 64);
    float inv = 1.0f / fmaxf(sqrtf(ss), 1e-8f);
    float o[8] = {v0.x*inv, v0.y*inv, v0.z*inv, v0.w*inv,
                  v1.x*inv, v1.y*inv, v1.z*inv, v1.w*inv};
#pragma unroll
    for (int i = 0; i < 8; ++i) {
        an[e * D_DIM + lane * 8 + i] = o[i];
        dout_an[e * D_DIM + lane * 8 + i] = o[i];
    }
}

// ---------------- routing: scores, top-2, gates -----------------------------
__global__ void routing_k(const float* __restrict__ x, const float* __restrict__ an,
                          float* __restrict__ dout_scores, float* __restrict__ dout_idx,
                          int* __restrict__ idxs, float* __restrict__ gates,
                          int* __restrict__ cnt) {
    __shared__ float anl[E_EXP * D_DIM];
    int tid = threadIdx.x;
    for (int i = tid; i < E_EXP * D_DIM; i += 256) anl[i] = an[i];
    __syncthreads();
    int lane = tid & 63, w = tid >> 6;
    int t = blockIdx.x * 4 + w;
    const float4* xr = (const float4*)(x + (size_t)t * D_DIM + lane * 8);
    float4 a = xr[0], b = xr[1];
    float xv[8] = {a.x, a.y, a.z, a.w, b.x, b.y, b.z, b.w};
    float ss = 0.f;
#pragma unroll
    for (int i = 0; i < 8; ++i) ss += xv[i] * xv[i];
    float p[E_EXP];
#pragma unroll
    for (int e = 0; e < E_EXP; ++e) {
        float s = 0.f;
#pragma unroll
        for (int i = 0; i < 8; ++i) s += xv[i] * anl[e * D_DIM + lane * 8 + i];
        p[e] = s;
    }
#pragma unroll
    for (int off = 32; off >= 1; off >>= 1) {
        ss += __shfl_xor(ss, off, 64);
#pragma unroll
        for (int e = 0; e < E_EXP; ++e) p[e] += __shfl_xor(p[e], off, 64);
    }
    float inv = 1.0f / fmaxf(sqrtf(ss), 1e-8f);
    float s[E_EXP];
#pragma unroll
    for (int e = 0; e < E_EXP; ++e) s[e] = p[e] * inv;
    // top-2, ties -> lowest index (matches jax.lax.top_k)
    int i0 = 0; float b0 = s[0];
#pragma unroll
    for (int e = 1; e < E_EXP; ++e) if (s[e] > b0) { b0 = s[e]; i0 = e; }
    int i1 = -1; float b1v = -1e30f;
#pragma unroll
    for (int e = 0; e < E_EXP; ++e)
        if (e != i0 && s[e] > b1v) { b1v = s[e]; i1 = e; }
    if (i1 < 0) { i1 = (i0 + 1) & 7; b1v = s[i1]; }   // NaN-safety: never -1
    float g0 = 1.0f / (1.0f + expf(b1v - b0));
    float g1 = 1.0f - g0;
    if (lane < E_EXP) dout_scores[t * E_EXP + lane] = s[lane];
    if (lane == 0) {
        dout_idx[t * 2 + 0] = (float)i0;
        dout_idx[t * 2 + 1] = (float)i1;
        idxs[t * 2 + 0] = i0; idxs[t * 2 + 1] = i1;
        gates[t * 2 + 0] = g0; gates[t * 2 + 1] = g1;
        atomicAdd(&cnt[i0], 1);
        atomicAdd(&cnt[i1], 1);
    }
}

// ---------------- offsets (128-padded) + cursors ----------------------------
__global__ void offs_k(const int* __restrict__ cnt, int* __restrict__ offs,
                       int* __restrict__ cur) {
    if (threadIdx.x == 0 && blockIdx.x == 0) {
        int acc = 0;
        for (int e = 0; e < E_EXP; ++e) {
            offs[e] = acc; cur[e] = acc;
            acc += (cnt[e] + 127) & ~127;
        }
        offs[E_EXP] = acc;
    }
}

// ---------------- slot assignment (bounds-clamped) --------------------------
__global__ void assign_k(const int* __restrict__ idxs, const float* __restrict__ gates,
                         int* __restrict__ cur, int* __restrict__ rowmap,
                         float* __restrict__ rowgate) {
    int t = blockIdx.x * 256 + threadIdx.x;
    if (t >= T_TOK) return;
#pragma unroll
    for (int k = 0; k < 2; ++k) {
        int e = idxs[t * 2 + k];
        e = min(max(e, 0), E_EXP - 1);
        int r = atomicAdd(&cur[e], 1);
        if (r >= 0 && r < NROWS) {
            rowmap[r] = t;
            rowgate[r] = gates[t * 2 + k];
        }
    }
}

// ---------------- VALU grouped GEMM ----------------------------------------
// MODE 0: Hg[r,:] = bf16(gelu(x[rowmap[r],:] @ W1e + b1e))   (N=F, K=D)
// MODE 1: outacc[rowmap[r],:] += rowgate[r] * (Hg[r,:] @ W2e) (N=D, K=F)
// 64x64 tile, K-chunk 32, 256 threads (16x16), 4x4 outputs/thread, fp32.
template <int MODE>
__global__ void vgemm_k(const float* __restrict__ x, const u16* __restrict__ Hg,
                        const float* __restrict__ Wbase, const float* __restrict__ b1,
                        u16* __restrict__ Hout, float* __restrict__ outacc,
                        const int* __restrict__ rowmap, const float* __restrict__ rowgate,
                        const int* __restrict__ offs) {
    int row0 = blockIdx.y * 64;
    if (row0 >= offs[E_EXP]) return;
    int e = 0;
#pragma unroll
    for (int i = 1; i < E_EXP; ++i) if (row0 >= offs[i]) e = i;
    const int K = (MODE == 0) ? D_DIM : F_DIM;
    const int N = (MODE == 0) ? F_DIM : D_DIM;
    const float* B = Wbase + (size_t)e * D_DIM * F_DIM;
    int n0 = blockIdx.x * 64;

    __shared__ float As[64][36];   // [row][k]
    __shared__ float Bs[32][68];   // [k][col]

    int tid = threadIdx.x;
    int tx = tid & 15, ty = tid >> 4;
    int ar = tid >> 2, ac = (tid & 3) * 4;   // A loader: row, k-offset
    int bk = tid >> 4, bc = (tid & 15) * 4;  // B loader: k-row, col-offset

    int tokA = (MODE == 0) ? rowmap[row0 + ar] : 0;

    float acc[4][4] = {};

    for (int k0 = 0; k0 < K; k0 += 32) {
        float4 av0, av1;
        if (MODE == 0) {
            if (tokA < 0) {
                av0 = float4{0.f, 0.f, 0.f, 0.f};
                av1 = float4{0.f, 0.f, 0.f, 0.f};
            } else {
                const float* xp = x + (size_t)tokA * D_DIM + k0 + ac;
                av0 = *(const float4*)xp;
                av1 = *(const float4*)(xp + 16);
            }
        } else {
            const u16* hp = Hg + (size_t)(row0 + ar) * F_DIM + k0 + ac;
            ushort4 h0 = *(const ushort4*)hp;
            ushort4 h1 = *(const ushort4*)(hp + 16);
            av0 = float4{b2f(h0.x), b2f(h0.y), b2f(h0.z), b2f(h0.w)};
            av1 = float4{b2f(h1.x), b2f(h1.y), b2f(h1.z), b2f(h1.w)};
        }
        *(float4*)&As[ar][ac]      = av0;
        *(float4*)&As[ar][ac + 16] = av1;
        const float* bp0 = B + (size_t)(k0 + bk) * N + n0 + bc;
        const float* bp1 = B + (size_t)(k0 + bk + 16) * N + n0 + bc;
        float4 bv0 = *(const float4*)bp0;
        float4 bv1 = *(const float4*)bp1;
        *(float4*)&Bs[bk][bc]      = bv0;
        *(float4*)&Bs[bk + 16][bc] = bv1;
        __syncthreads();
#pragma unroll
        for (int kk = 0; kk < 32; ++kk) {
            float a0 = As[ty * 4 + 0][kk];
            float a1 = As[ty * 4 + 1][kk];
            float a2 = As[ty * 4 + 2][kk];
            float a3 = As[ty * 4 + 3][kk];
            float4 b4 = *(const float4*)&Bs[kk][tx * 4];
            acc[0][0] += a0 * b4.x; acc[0][1] += a0 * b4.y;
            acc[0][2] += a0 * b4.z; acc[0][3] += a0 * b4.w;
            acc[1][0] += a1 * b4.x; acc[1][1] += a1 * b4.y;
            acc[1][2] += a1 * b4.z; acc[1][3] += a1 * b4.w;
            acc[2][0] += a2 * b4.x; acc[2][1] += a2 * b4.y;
            acc[2][2] += a2 * b4.z; acc[2][3] += a2 * b4.w;
            acc[3][0] += a3 * b4.x; acc[3][1] += a3 * b4.y;
            acc[3][2] += a3 * b4.z; acc[3][3] += a3 * b4.w;
        }
        __syncthreads();
    }

    if constexpr (MODE == 0) {
        const float* b1e = b1 + (size_t)e * F_DIM;
#pragma unroll
        for (int i = 0; i < 4; ++i) {
            int gr = row0 + ty * 4 + i;
            int gc = n0 + tx * 4;
            float v0 = acc[i][0] + b1e[gc + 0];
            float v1 = acc[i][1] + b1e[gc + 1];
            float v2 = acc[i][2] + b1e[gc + 2];
            float v3 = acc[i][3] + b1e[gc + 3];
            ushort4 o;
            o.x = f2b(0.5f * v0 * (1.0f + erff(v0 * 0.70710678118f)));
            o.y = f2b(0.5f * v1 * (1.0f + erff(v1 * 0.70710678118f)));
            o.z = f2b(0.5f * v2 * (1.0f + erff(v2 * 0.70710678118f)));
            o.w = f2b(0.5f * v3 * (1.0f + erff(v3 * 0.70710678118f)));
            *(ushort4*)(Hout + (size_t)gr * F_DIM + gc) = o;
        }
    } else {
#pragma unroll
        for (int i = 0; i < 4; ++i) {
            int gr = row0 + ty * 4 + i;
            int tok = rowmap[gr];
            if (tok < 0 || tok >= T_TOK) continue;
            float g = rowgate[gr];
            float* orow = outacc + (size_t)tok * D_DIM + n0 + tx * 4;
#pragma unroll
            for (int j = 0; j < 4; ++j) atomicAdd(orow + j, g * acc[i][j]);
        }
    }
}

// ---------------- final: out = outacc + g0*b2[i0] + g1*b2[i1] (fp32) --------
__global__ void final_k(const float* __restrict__ outacc, const int* __restrict__ idxs,
                        const float* __restrict__ gates, const float* __restrict__ b2,
                        float* __restrict__ dout) {
    int t = blockIdx.x;
    int i0 = min(max(idxs[t * 2], 0), E_EXP - 1);
    int i1 = min(max(idxs[t * 2 + 1], 0), E_EXP - 1);
    float g0 = gates[t * 2], g1 = gates[t * 2 + 1];
    int d = threadIdx.x * 2;
    float2 oa = *(const float2*)(outacc + (size_t)t * D_DIM + d);
    const float* p0 = b2 + (size_t)i0 * D_DIM + d;
    const float* p1 = b2 + (size_t)i1 * D_DIM + d;
    float2 o;
    o.x = oa.x + g0 * p0[0] + g1 * p1[0];
    o.y = oa.y + g0 * p0[1] + g1 * p1[1];
    *(float2*)(dout + (size_t)t * D_DIM + d) = o;
}

// ---------------- workspace layout (bytes) — total need ~47.2 MB ------------
#define OFF_AN      0u           // 16384  fp32 a_n
#define OFF_CNT     0x10000u
#define OFF_OFFS    0x10100u
#define OFF_CUR     0x10200u
#define OFF_IDX     0x20000u     // int[T*2]
#define OFF_GATE    0x28000u     // float[T*2]
#define OFF_ROWMAP  0x30000u     // int[NROWS]
#define OFF_ROWGATE 0x40000u     // float[NROWS]
#define OFF_OUTACC  0x100000u    // 8 MB fp32[T*D] -> ends 0x900000
#define OFF_HG      0x900000u    // 37.75 MB u16[NROWS*F] -> ends 0x2D00000

extern "C" void kernel_launch(void* const* d_in, const int* in_sizes, int n_in,
                              void* d_out, int out_size, void* d_ws, size_t ws_size,
                              hipStream_t stream) {
    const float* x       = (const float*)d_in[0];
    const float* anchors = (const float*)d_in[1];
    const float* W1      = (const float*)d_in[2];
    const float* b1      = (const float*)d_in[3];
    const float* W2      = (const float*)d_in[4];
    const float* b2      = (const float*)d_in[5];
    float* out = (float*)d_out;

    char* ws = (char*)d_ws;
    float* an      = (float*)(ws + OFF_AN);
    int*   cnt     = (int*)(ws + OFF_CNT);
    int*   offs    = (int*)(ws + OFF_OFFS);
    int*   cur     = (int*)(ws + OFF_CUR);
    int*   idxs    = (int*)(ws + OFF_IDX);
    float* gates   = (float*)(ws + OFF_GATE);
    int*   rowmap  = (int*)(ws + OFF_ROWMAP);
    float* rowgate = (float*)(ws + OFF_ROWGATE);
    float* outacc  = (float*)(ws + OFF_OUTACC);
    u16*   Hg      = (u16*)(ws + OFF_HG);

    // d_out sections (fp32 elements): out | a_n | scores | topk_idx
    float* out_main   = out;
    float* out_an     = out + (size_t)T_TOK * D_DIM;
    float* out_scores = out_an + E_EXP * D_DIM;
    float* out_idx    = out_scores + (size_t)T_TOK * E_EXP;

    hipMemsetAsync(cnt, 0, E_EXP * sizeof(int), stream);
    hipMemsetAsync(rowmap, 0xFF, NROWS * sizeof(int), stream);
    hipMemsetAsync(rowgate, 0, NROWS * sizeof(float), stream);
    hipMemsetAsync(outacc, 0, (size_t)T_TOK * D_DIM * sizeof(float), stream);

    anchors_k<<<1, 512, 0, stream>>>(anchors, an, out_an);
    routing_k<<<T_TOK / 4, 256, 0, stream>>>(x, an, out_scores, out_idx,
                                             idxs, gates, cnt);
    offs_k<<<1, 64, 0, stream>>>(cnt, offs, cur);
    assign_k<<<T_TOK / 256, 256, 0, stream>>>(idxs, gates, cur, rowmap, rowgate);
    vgemm_k<0><<<dim3(F_DIM / 64, MTILES), 256, 0, stream>>>(
        x, nullptr, W1, b1, Hg, nullptr, rowmap, nullptr, offs);
    vgemm_k<1><<<dim3(D_DIM / 64, MTILES), 256, 0, stream>>>(
        nullptr, Hg, W2, nullptr, nullptr, outacc, rowmap, rowgate, offs);
    final_k<<<T_TOK, 256, 0, stream>>>(outacc, idxs, gates, b2, out_main);
}

// Round 8
// 372.676 us; speedup vs baseline: 1.9905x; 1.9905x over previous
//
#include <hip/hip_runtime.h>
#include <cstdint>

// ---------------------------------------------------------------------------
// Round 8: fp32 in/out (proven round 7) + MFMA grouped-GEMM pipeline
// (machinery crash-proven in round 2; MFMA core A/B-validated vs VALU GEMM).
// routing -> offsets -> assign -> gather(cast bf16) -> transpose-cast(W) ->
//   GEMM1 (Xg @ W1e^T, +b1 fp32, exact GELU) -> Hg bf16 ->
//   GEMM2 (Hg @ W2e^T, split-K=2) -> gate-scaled fp32 atomic scatter ->
//   final (+ gate-weighted b2) -> fp32 out.
// GEMM: 128x128xBK64, 4 waves (2x2), mfma_f32_16x16x32_bf16,
// global_load_lds(16B), linear [m][kc] LDS layout, alignas(16).
// ---------------------------------------------------------------------------

#define T_TOK 4096
#define D_DIM 512
#define F_DIM 2048
#define E_EXP 8
#define NROWS 9216      // 8192 assignments + 8*128 pad
#define MAXTILES 72     // NROWS / 128

typedef __bf16 bf16x8 __attribute__((ext_vector_type(8)));
typedef float  f32x4  __attribute__((ext_vector_type(4)));
typedef unsigned short u16;

__device__ __forceinline__ u16 f2b(float f) {
    return __builtin_bit_cast(unsigned short, (__bf16)f);
}
__device__ __forceinline__ float b2f(u16 v) {
    unsigned int u = ((unsigned int)v) << 16;
    return __builtin_bit_cast(float, u);
}
__device__ __forceinline__ void gload16(void* lds, const void* g) {
    __builtin_amdgcn_global_load_lds(
        (const __attribute__((address_space(1))) void*)g,
        (__attribute__((address_space(3))) void*)lds, 16, 0, 0);
}

// ---------------- anchors: a_n = a / max(||a||, eps) ------------------------
__global__ void anchors_k(const float* __restrict__ anchors,
                          float* __restrict__ an, float* __restrict__ dout_an) {
    int tid = threadIdx.x;           // 512 threads = 8 waves, wave e = anchor e
    int lane = tid & 63, e = tid >> 6;
    const float4* ar = (const float4*)(anchors + e * D_DIM + lane * 8);
    float4 v0 = ar[0], v1 = ar[1];
    float ss = v0.x*v0.x + v0.y*v0.y + v0.z*v0.z + v0.w*v0.w
             + v1.x*v1.x + v1.y*v1.y + v1.z*v1.z + v1.w*v1.w;
#pragma unroll
    for (int off = 32; off >= 1; off >>= 1) ss += __shfl_xor(ss, off, 64);
    float inv = 1.0f / fmaxf(sqrtf(ss), 1e-8f);
    float o[8] = {v0.x*inv, v0.y*inv, v0.z*inv, v0.w*inv,
                  v1.x*inv, v1.y*inv, v1.z*inv, v1.w*inv};
#pragma unroll
    for (int i = 0; i < 8; ++i) {
        an[e * D_DIM + lane * 8 + i] = o[i];
        dout_an[e * D_DIM + lane * 8 + i] = o[i];
    }
}

// ---------------- routing: scores, top-2, gates -----------------------------
__global__ void routing_k(const float* __restrict__ x, const float* __restrict__ an,
                          float* __restrict__ dout_scores, float* __restrict__ dout_idx,
                          int* __restrict__ idxs, float* __restrict__ gates,
                          int* __restrict__ cnt) {
    __shared__ float anl[E_EXP * D_DIM];
    int tid = threadIdx.x;
    for (int i = tid; i < E_EXP * D_DIM; i += 256) anl[i] = an[i];
    __syncthreads();
    int lane = tid & 63, w = tid >> 6;
    int t = blockIdx.x * 4 + w;
    const float4* xr = (const float4*)(x + (size_t)t * D_DIM + lane * 8);
    float4 a = xr[0], b = xr[1];
    float xv[8] = {a.x, a.y, a.z, a.w, b.x, b.y, b.z, b.w};
    float ss = 0.f;
#pragma unroll
    for (int i = 0; i < 8; ++i) ss += xv[i] * xv[i];
    float p[E_EXP];
#pragma unroll
    for (int e = 0; e < E_EXP; ++e) {
        float s = 0.f;
#pragma unroll
        for (int i = 0; i < 8; ++i) s += xv[i] * anl[e * D_DIM + lane * 8 + i];
        p[e] = s;
    }
#pragma unroll
    for (int off = 32; off >= 1; off >>= 1) {
        ss += __shfl_xor(ss, off, 64);
#pragma unroll
        for (int e = 0; e < E_EXP; ++e) p[e] += __shfl_xor(p[e], off, 64);
    }
    float inv = 1.0f / fmaxf(sqrtf(ss), 1e-8f);
    float s[E_EXP];
#pragma unroll
    for (int e = 0; e < E_EXP; ++e) s[e] = p[e] * inv;
    // top-2, ties -> lowest index (matches jax.lax.top_k)
    int i0 = 0; float b0 = s[0];
#pragma unroll
    for (int e = 1; e < E_EXP; ++e) if (s[e] > b0) { b0 = s[e]; i0 = e; }
    int i1 = -1; float b1v = -1e30f;
#pragma unroll
    for (int e = 0; e < E_EXP; ++e)
        if (e != i0 && s[e] > b1v) { b1v = s[e]; i1 = e; }
    if (i1 < 0) { i1 = (i0 + 1) & 7; b1v = s[i1]; }   // NaN-safety: never -1
    float g0 = 1.0f / (1.0f + expf(b1v - b0));
    float g1 = 1.0f - g0;
    if (lane < E_EXP) dout_scores[t * E_EXP + lane] = s[lane];
    if (lane == 0) {
        dout_idx[t * 2 + 0] = (float)i0;
        dout_idx[t * 2 + 1] = (float)i1;
        idxs[t * 2 + 0] = i0; idxs[t * 2 + 1] = i1;
        gates[t * 2 + 0] = g0; gates[t * 2 + 1] = g1;
        atomicAdd(&cnt[i0], 1);
        atomicAdd(&cnt[i1], 1);
    }
}

// ---------------- offsets (128-padded) + cursors ----------------------------
__global__ void offs_k(const int* __restrict__ cnt, int* __restrict__ offs,
                       int* __restrict__ cur) {
    if (threadIdx.x == 0 && blockIdx.x == 0) {
        int acc = 0;
        for (int e = 0; e < E_EXP; ++e) {
            offs[e] = acc; cur[e] = acc;
            acc += (cnt[e] + 127) & ~127;
        }
        offs[E_EXP] = acc;
    }
}

// ---------------- slot assignment (bounds-clamped) --------------------------
__global__ void assign_k(const int* __restrict__ idxs, const float* __restrict__ gates,
                         int* __restrict__ cur, int* __restrict__ rowmap,
                         float* __restrict__ rowgate) {
    int t = blockIdx.x * 256 + threadIdx.x;
    if (t >= T_TOK) return;
#pragma unroll
    for (int k = 0; k < 2; ++k) {
        int e = idxs[t * 2 + k];
        e = min(max(e, 0), E_EXP - 1);
        int r = atomicAdd(&cur[e], 1);
        if (r >= 0 && r < NROWS) {
            rowmap[r] = t;
            rowgate[r] = gates[t * 2 + k];
        }
    }
}

// ---------------- gather tokens -> bf16 rows (pad rows zeroed) --------------
__global__ void gather_k(const float* __restrict__ x, const int* __restrict__ rowmap,
                         u16* __restrict__ Xg) {
    int r = blockIdx.x;
    int t = rowmap[r];
    int c = threadIdx.x * 2;     // 256 threads x 2 = 512 elems
    ushort2 o;
    if (t < 0 || t >= T_TOK) { o.x = 0; o.y = 0; }
    else {
        float2 v = *(const float2*)(x + (size_t)t * D_DIM + c);
        o.x = f2b(v.x); o.y = f2b(v.y);
    }
    *(ushort2*)(Xg + (size_t)r * D_DIM + c) = o;
}

// ---------------- transpose + cast fp32 [Z][R][C] -> bf16 [Z][C][R] ---------
__global__ void transpose_cast_k(const float* __restrict__ in, u16* __restrict__ out,
                                 int R, int C) {
    size_t zoff = (size_t)blockIdx.z * R * C;
    in += zoff; out += zoff;
    __shared__ float t[32][33];
    int c0 = blockIdx.x * 32, r0 = blockIdx.y * 32;
    int tx = threadIdx.x, ty = threadIdx.y;   // (32, 8)
#pragma unroll
    for (int j = 0; j < 32; j += 8)
        t[ty + j][tx] = in[(size_t)(r0 + ty + j) * C + c0 + tx];
    __syncthreads();
#pragma unroll
    for (int j = 0; j < 32; j += 8)
        out[(size_t)(c0 + ty + j) * R + r0 + tx] = f2b(t[tx][ty + j]);
}

// ---------------- grouped GEMM core (round-2-proven structure) --------------
// MODE 0: Hg = bf16(gelu(Xg @ W1e^T + b1e))   (N=F, K=D)
// MODE 1: outacc[tok] += gate * (Hg @ W2e^T)  (N=D, K=F, split-K via blockIdx.z)
// LDS: linear [m][kc], chunk (m,kc) (8 bf16 = 16B) at slot m*8+kc.
template <int MODE>
__launch_bounds__(256, 2)
__global__ void gemm_k(const u16* __restrict__ A, int lda,
                       const u16* __restrict__ BtBase, int ldb,
                       u16* __restrict__ Hout, const float* __restrict__ b1,
                       float* __restrict__ outacc,
                       const int* __restrict__ rowmap, const float* __restrict__ rowgate,
                       const int* __restrict__ offs, int kPer) {
    int row0 = blockIdx.y * 128;
    if (row0 >= offs[E_EXP]) return;
    int e = 0;
#pragma unroll
    for (int i = 1; i < E_EXP; ++i) if (row0 >= offs[i]) e = i;
    const u16* Bt = BtBase + (size_t)e * D_DIM * F_DIM;
    int n0 = blockIdx.x * 128;
    int k_begin = (MODE == 1) ? (int)blockIdx.z * kPer : 0;
    int k_end = k_begin + kPer;

    alignas(16) __shared__ u16 As[128 * 64];
    alignas(16) __shared__ u16 Bs[128 * 64];

    int tid = threadIdx.x;
    int lane = tid & 63;
    int wv = tid >> 6;
    int wm = wv & 1, wn = wv >> 1;
    int kq = lane >> 4;          // quad 0..3
    int l15 = lane & 15;

    // staging: slot = i*256 + tid; m = slot>>3; kc = slot&7 (linear)
    const u16* aSrc[4]; const u16* bSrc[4];
    u16* aDst[4]; u16* bDst[4];
#pragma unroll
    for (int i = 0; i < 4; ++i) {
        int slot = i * 256 + tid;
        int m = slot >> 3;
        int kc = slot & 7;
        aSrc[i] = A + (size_t)(row0 + m) * lda + kc * 8;
        bSrc[i] = Bt + (size_t)(n0 + m) * ldb + kc * 8;
        aDst[i] = As + slot * 8;
        bDst[i] = Bs + slot * 8;
    }

    f32x4 acc[4][4];
#pragma unroll
    for (int i = 0; i < 4; ++i)
#pragma unroll
        for (int j = 0; j < 4; ++j) acc[i][j] = f32x4{0.f, 0.f, 0.f, 0.f};

    for (int k0 = k_begin; k0 < k_end; k0 += 64) {
#pragma unroll
        for (int i = 0; i < 4; ++i) gload16(aDst[i], aSrc[i] + k0);
#pragma unroll
        for (int i = 0; i < 4; ++i) gload16(bDst[i], bSrc[i] + k0);
        asm volatile("s_waitcnt vmcnt(0)" ::: "memory");
        __syncthreads();
#pragma unroll
        for (int kk = 0; kk < 2; ++kk) {
            int kc = kk * 4 + kq;
            bf16x8 af[4], bfr[4];
#pragma unroll
            for (int i = 0; i < 4; ++i) {
                int rowA = wm * 64 + i * 16 + l15;
                af[i] = *(const bf16x8*)(As + rowA * 64 + kc * 8);
                int rowB = wn * 64 + i * 16 + l15;
                bfr[i] = *(const bf16x8*)(Bs + rowB * 64 + kc * 8);
            }
#pragma unroll
            for (int i = 0; i < 4; ++i)
#pragma unroll
                for (int j = 0; j < 4; ++j)
                    acc[i][j] = __builtin_amdgcn_mfma_f32_16x16x32_bf16(
                        af[i], bfr[j], acc[i][j], 0, 0, 0);
        }
        __syncthreads();
    }

    if constexpr (MODE == 0) {
        const float* b1e = b1 + (size_t)e * F_DIM;
#pragma unroll
        for (int i = 0; i < 4; ++i) {
            int gr = row0 + wm * 64 + i * 16 + kq * 4;
#pragma unroll
            for (int j = 0; j < 4; ++j) {
                int gc = n0 + wn * 64 + j * 16 + l15;
                float bb = b1e[gc];
#pragma unroll
                for (int r = 0; r < 4; ++r) {
                    float v = acc[i][j][r] + bb;
                    float h = 0.5f * v * (1.0f + erff(v * 0.70710678118f));
                    Hout[(size_t)(gr + r) * F_DIM + gc] = f2b(h);
                }
            }
        }
    } else {
#pragma unroll
        for (int i = 0; i < 4; ++i) {
            int grb = row0 + wm * 64 + i * 16 + kq * 4;
#pragma unroll
            for (int r = 0; r < 4; ++r) {
                int tok = rowmap[grb + r];
                float g = rowgate[grb + r];
                if (tok >= 0 && tok < T_TOK) {
                    float* orow = outacc + (size_t)tok * D_DIM;
#pragma unroll
                    for (int j = 0; j < 4; ++j) {
                        int gc = n0 + wn * 64 + j * 16 + l15;
                        atomicAdd(orow + gc, g * acc[i][j][r]);
                    }
                }
            }
        }
    }
}

// ---------------- final: out = outacc + g0*b2[i0] + g1*b2[i1] (fp32) --------
__global__ void final_k(const float* __restrict__ outacc, const int* __restrict__ idxs,
                        const float* __restrict__ gates, const float* __restrict__ b2,
                        float* __restrict__ dout) {
    int t = blockIdx.x;
    int i0 = min(max(idxs[t * 2], 0), E_EXP - 1);
    int i1 = min(max(idxs[t * 2 + 1], 0), E_EXP - 1);
    float g0 = gates[t * 2], g1 = gates[t * 2 + 1];
    int d = threadIdx.x * 2;
    float2 oa = *(const float2*)(outacc + (size_t)t * D_DIM + d);
    const float* p0 = b2 + (size_t)i0 * D_DIM + d;
    const float* p1 = b2 + (size_t)i1 * D_DIM + d;
    float2 o;
    o.x = oa.x + g0 * p0[0] + g1 * p1[0];
    o.y = oa.y + g0 * p0[1] + g1 * p1[1];
    *(float2*)(dout + (size_t)t * D_DIM + d) = o;
}

// ---------------- workspace layout (bytes) — total need ~86 MB --------------
#define OFF_AN      0u           // 16 KB fp32 a_n
#define OFF_CNT     0x10000u
#define OFF_OFFS    0x10100u
#define OFF_CUR     0x10200u
#define OFF_IDX     0x20000u     // int[T*2]
#define OFF_GATE    0x28000u     // float[T*2]
#define OFF_ROWMAP  0x30000u     // int[NROWS]
#define OFF_ROWGATE 0x40000u     // float[NROWS]
#define OFF_OUTACC  0x50000u     // 8 MB fp32[T*D]   -> ends 0x850000
#define OFF_XG      0x900000u    // 9.44 MB u16[NROWS*D]  -> ends 0x1200000
#define OFF_W1T     0x1200000u   // 16.78 MB u16[E][F][D] -> ends 0x2200000
#define OFF_W2T     0x2200000u   // 16.78 MB u16[E][D][F] -> ends 0x3200000
#define OFF_HG      0x3200000u   // 37.75 MB u16[NROWS*F] -> ends 0x5600000

extern "C" void kernel_launch(void* const* d_in, const int* in_sizes, int n_in,
                              void* d_out, int out_size, void* d_ws, size_t ws_size,
                              hipStream_t stream) {
    const float* x       = (const float*)d_in[0];
    const float* anchors = (const float*)d_in[1];
    const float* W1      = (const float*)d_in[2];
    const float* b1      = (const float*)d_in[3];
    const float* W2      = (const float*)d_in[4];
    const float* b2      = (const float*)d_in[5];
    float* out = (float*)d_out;

    char* ws = (char*)d_ws;
    float* an      = (float*)(ws + OFF_AN);
    int*   cnt     = (int*)(ws + OFF_CNT);
    int*   offs    = (int*)(ws + OFF_OFFS);
    int*   cur     = (int*)(ws + OFF_CUR);
    int*   idxs    = (int*)(ws + OFF_IDX);
    float* gates   = (float*)(ws + OFF_GATE);
    int*   rowmap  = (int*)(ws + OFF_ROWMAP);
    float* rowgate = (float*)(ws + OFF_ROWGATE);
    float* outacc  = (float*)(ws + OFF_OUTACC);
    u16*   Xg      = (u16*)(ws + OFF_XG);
    u16*   W1T     = (u16*)(ws + OFF_W1T);
    u16*   W2T     = (u16*)(ws + OFF_W2T);
    u16*   Hg      = (u16*)(ws + OFF_HG);

    // d_out sections (fp32 elements): out | a_n | scores | topk_idx
    float* out_main   = out;
    float* out_an     = out + (size_t)T_TOK * D_DIM;
    float* out_scores = out_an + E_EXP * D_DIM;
    float* out_idx    = out_scores + (size_t)T_TOK * E_EXP;

    hipMemsetAsync(cnt, 0, E_EXP * sizeof(int), stream);
    hipMemsetAsync(rowmap, 0xFF, NROWS * sizeof(int), stream);
    hipMemsetAsync(rowgate, 0, NROWS * sizeof(float), stream);
    hipMemsetAsync(outacc, 0, (size_t)T_TOK * D_DIM * sizeof(float), stream);

    anchors_k<<<1, 512, 0, stream>>>(anchors, an, out_an);
    routing_k<<<T_TOK / 4, 256, 0, stream>>>(x, an, out_scores, out_idx,
                                             idxs, gates, cnt);
    offs_k<<<1, 64, 0, stream>>>(cnt, offs, cur);
    assign_k<<<T_TOK / 256, 256, 0, stream>>>(idxs, gates, cur, rowmap, rowgate);
    gather_k<<<NROWS, 256, 0, stream>>>(x, rowmap, Xg);
    // W1 [E][D][F] -> W1T [E][F][D];  W2 [E][F][D] -> W2T [E][D][F]
    transpose_cast_k<<<dim3(F_DIM / 32, D_DIM / 32, E_EXP), dim3(32, 8), 0, stream>>>(
        W1, W1T, D_DIM, F_DIM);
    transpose_cast_k<<<dim3(D_DIM / 32, F_DIM / 32, E_EXP), dim3(32, 8), 0, stream>>>(
        W2, W2T, F_DIM, D_DIM);
    gemm_k<0><<<dim3(F_DIM / 128, MAXTILES, 1), 256, 0, stream>>>(
        Xg, D_DIM, W1T, D_DIM, Hg, b1, nullptr, rowmap, nullptr, offs, D_DIM);
    gemm_k<1><<<dim3(D_DIM / 128, MAXTILES, 2), 256, 0, stream>>>(
        Hg, F_DIM, W2T, F_DIM, nullptr, nullptr, outacc, rowmap, rowgate,
        offs, F_DIM / 2);
    final_k<<<T_TOK, 256, 0, stream>>>(outacc, idxs, gates, b2, out_main);
}

// Round 9
// 288.071 us; speedup vs baseline: 2.5751x; 1.2937x over previous
//
#include <hip/hip_runtime.h>
#include <cstdint>

// ---------------------------------------------------------------------------
// Round 9: round-8 pipeline (372 µs) with routing_k rewritten.
// Old routing: 1 wave/token, 54 chained wave-wide shuffles + 16-way-conflicted
// LDS reads -> 100 µs at 2.3% VALUBusy (latency-bound).
// New routing: 4 threads/token, register dot-products over 128-dim quarters,
// bank-padded LDS anchor broadcast, 2-step quad shuffle reduce, LDS histogram.
// ---------------------------------------------------------------------------

#define T_TOK 4096
#define D_DIM 512
#define F_DIM 2048
#define E_EXP 8
#define NROWS 9216      // 8192 assignments + 8*128 pad
#define MAXTILES 72     // NROWS / 128

typedef __bf16 bf16x8 __attribute__((ext_vector_type(8)));
typedef float  f32x4  __attribute__((ext_vector_type(4)));
typedef unsigned short u16;

__device__ __forceinline__ u16 f2b(float f) {
    return __builtin_bit_cast(unsigned short, (__bf16)f);
}
__device__ __forceinline__ void gload16(void* lds, const void* g) {
    __builtin_amdgcn_global_load_lds(
        (const __attribute__((address_space(1))) void*)g,
        (__attribute__((address_space(3))) void*)lds, 16, 0, 0);
}

// ---------------- anchors: a_n = a / max(||a||, eps) ------------------------
__global__ void anchors_k(const float* __restrict__ anchors,
                          float* __restrict__ an, float* __restrict__ dout_an) {
    int tid = threadIdx.x;           // 512 threads = 8 waves, wave e = anchor e
    int lane = tid & 63, e = tid >> 6;
    const float4* ar = (const float4*)(anchors + e * D_DIM + lane * 8);
    float4 v0 = ar[0], v1 = ar[1];
    float ss = v0.x*v0.x + v0.y*v0.y + v0.z*v0.z + v0.w*v0.w
             + v1.x*v1.x + v1.y*v1.y + v1.z*v1.z + v1.w*v1.w;
#pragma unroll
    for (int off = 32; off >= 1; off >>= 1) ss += __shfl_xor(ss, off, 64);
    float inv = 1.0f / fmaxf(sqrtf(ss), 1e-8f);
    float o[8] = {v0.x*inv, v0.y*inv, v0.z*inv, v0.w*inv,
                  v1.x*inv, v1.y*inv, v1.z*inv, v1.w*inv};
#pragma unroll
    for (int i = 0; i < 8; ++i) {
        an[e * D_DIM + lane * 8 + i] = o[i];
        dout_an[e * D_DIM + lane * 8 + i] = o[i];
    }
}

// ---------------- routing: 4 threads per token ------------------------------
// thread (tid>>2)=local token, (tid&3)=dim quarter p (128 dims each).
// anchors in LDS with quarter stride 136 floats (136 mod 32 = 8 -> the four
// p-broadcast groups hit distinct banks; conflict-free b128 reads).
__global__ void routing_k(const float* __restrict__ x, const float* __restrict__ an,
                          float* __restrict__ dout_scores, float* __restrict__ dout_idx,
                          int* __restrict__ idxs, float* __restrict__ gates,
                          int* __restrict__ cnt) {
    __shared__ float anl[E_EXP * 544];   // [e][p*136 + i], i<128
    __shared__ int hist[E_EXP];
    int tid = threadIdx.x;
    if (tid < E_EXP) hist[tid] = 0;
    for (int i = tid; i < E_EXP * D_DIM; i += 256) {
        int e = i >> 9, d = i & 511;
        anl[e * 544 + (d >> 7) * 136 + (d & 127)] = an[i];
    }
    __syncthreads();

    int p = tid & 3;
    int tok = blockIdx.x * 64 + (tid >> 2);
    const float4* xr = (const float4*)(x + (size_t)tok * D_DIM + p * 128);
    const float* ab = &anl[p * 136];
    float dot[E_EXP] = {};
    float ss = 0.f;
    for (int c = 0; c < 32; ++c) {
        float4 xv = xr[c];
        ss += xv.x*xv.x + xv.y*xv.y + xv.z*xv.z + xv.w*xv.w;
#pragma unroll
        for (int e = 0; e < E_EXP; ++e) {
            float4 av = *(const float4*)&ab[e * 544 + c * 4];
            dot[e] += xv.x*av.x + xv.y*av.y + xv.z*av.z + xv.w*av.w;
        }
    }
#pragma unroll
    for (int off = 1; off <= 2; off <<= 1) {
        ss += __shfl_xor(ss, off, 64);
#pragma unroll
        for (int e = 0; e < E_EXP; ++e) dot[e] += __shfl_xor(dot[e], off, 64);
    }

    if (p == 0) {
        float inv = 1.0f / fmaxf(sqrtf(ss), 1e-8f);
        float s[E_EXP];
#pragma unroll
        for (int e = 0; e < E_EXP; ++e) s[e] = dot[e] * inv;
        // top-2, ties -> lowest index (matches jax.lax.top_k)
        int i0 = 0; float b0 = s[0];
#pragma unroll
        for (int e = 1; e < E_EXP; ++e) if (s[e] > b0) { b0 = s[e]; i0 = e; }
        int i1 = -1; float b1v = -1e30f;
#pragma unroll
        for (int e = 0; e < E_EXP; ++e)
            if (e != i0 && s[e] > b1v) { b1v = s[e]; i1 = e; }
        if (i1 < 0) { i1 = (i0 + 1) & 7; b1v = s[i1]; }   // NaN-safety
        float g0 = 1.0f / (1.0f + expf(b1v - b0));
        float g1 = 1.0f - g0;
#pragma unroll
        for (int e = 0; e < E_EXP; ++e) dout_scores[tok * E_EXP + e] = s[e];
        dout_idx[tok * 2 + 0] = (float)i0;
        dout_idx[tok * 2 + 1] = (float)i1;
        idxs[tok * 2 + 0] = i0; idxs[tok * 2 + 1] = i1;
        gates[tok * 2 + 0] = g0; gates[tok * 2 + 1] = g1;
        atomicAdd(&hist[i0], 1);
        atomicAdd(&hist[i1], 1);
    }
    __syncthreads();
    if (tid < E_EXP) atomicAdd(&cnt[tid], hist[tid]);
}

// ---------------- offsets (128-padded) + cursors ----------------------------
__global__ void offs_k(const int* __restrict__ cnt, int* __restrict__ offs,
                       int* __restrict__ cur) {
    if (threadIdx.x == 0 && blockIdx.x == 0) {
        int acc = 0;
        for (int e = 0; e < E_EXP; ++e) {
            offs[e] = acc; cur[e] = acc;
            acc += (cnt[e] + 127) & ~127;
        }
        offs[E_EXP] = acc;
    }
}

// ---------------- slot assignment (bounds-clamped) --------------------------
__global__ void assign_k(const int* __restrict__ idxs, const float* __restrict__ gates,
                         int* __restrict__ cur, int* __restrict__ rowmap,
                         float* __restrict__ rowgate) {
    int t = blockIdx.x * 256 + threadIdx.x;
    if (t >= T_TOK) return;
#pragma unroll
    for (int k = 0; k < 2; ++k) {
        int e = idxs[t * 2 + k];
        e = min(max(e, 0), E_EXP - 1);
        int r = atomicAdd(&cur[e], 1);
        if (r >= 0 && r < NROWS) {
            rowmap[r] = t;
            rowgate[r] = gates[t * 2 + k];
        }
    }
}

// ---------------- gather tokens -> bf16 rows (pad rows zeroed) --------------
__global__ void gather_k(const float* __restrict__ x, const int* __restrict__ rowmap,
                         u16* __restrict__ Xg) {
    int r = blockIdx.x;
    int t = rowmap[r];
    int c = threadIdx.x * 2;     // 256 threads x 2 = 512 elems
    ushort2 o;
    if (t < 0 || t >= T_TOK) { o.x = 0; o.y = 0; }
    else {
        float2 v = *(const float2*)(x + (size_t)t * D_DIM + c);
        o.x = f2b(v.x); o.y = f2b(v.y);
    }
    *(ushort2*)(Xg + (size_t)r * D_DIM + c) = o;
}

// ---------------- transpose + cast fp32 [Z][R][C] -> bf16 [Z][C][R] ---------
__global__ void transpose_cast_k(const float* __restrict__ in, u16* __restrict__ out,
                                 int R, int C) {
    size_t zoff = (size_t)blockIdx.z * R * C;
    in += zoff; out += zoff;
    __shared__ float t[32][33];
    int c0 = blockIdx.x * 32, r0 = blockIdx.y * 32;
    int tx = threadIdx.x, ty = threadIdx.y;   // (32, 8)
#pragma unroll
    for (int j = 0; j < 32; j += 8)
        t[ty + j][tx] = in[(size_t)(r0 + ty + j) * C + c0 + tx];
    __syncthreads();
#pragma unroll
    for (int j = 0; j < 32; j += 8)
        out[(size_t)(c0 + ty + j) * R + r0 + tx] = f2b(t[tx][ty + j]);
}

// ---------------- grouped GEMM core -----------------------------------------
// MODE 0: Hg = bf16(gelu(Xg @ W1e^T + b1e))   (N=F, K=D)
// MODE 1: outacc[tok] += gate * (Hg @ W2e^T)  (N=D, K=F, split-K via blockIdx.z)
// LDS: linear [m][kc], chunk (m,kc) (8 bf16 = 16B) at slot m*8+kc.
template <int MODE>
__launch_bounds__(256, 2)
__global__ void gemm_k(const u16* __restrict__ A, int lda,
                       const u16* __restrict__ BtBase, int ldb,
                       u16* __restrict__ Hout, const float* __restrict__ b1,
                       float* __restrict__ outacc,
                       const int* __restrict__ rowmap, const float* __restrict__ rowgate,
                       const int* __restrict__ offs, int kPer) {
    int row0 = blockIdx.y * 128;
    if (row0 >= offs[E_EXP]) return;
    int e = 0;
#pragma unroll
    for (int i = 1; i < E_EXP; ++i) if (row0 >= offs[i]) e = i;
    const u16* Bt = BtBase + (size_t)e * D_DIM * F_DIM;
    int n0 = blockIdx.x * 128;
    int k_begin = (MODE == 1) ? (int)blockIdx.z * kPer : 0;
    int k_end = k_begin + kPer;

    alignas(16) __shared__ u16 As[128 * 64];
    alignas(16) __shared__ u16 Bs[128 * 64];

    int tid = threadIdx.x;
    int lane = tid & 63;
    int wv = tid >> 6;
    int wm = wv & 1, wn = wv >> 1;
    int kq = lane >> 4;          // quad 0..3
    int l15 = lane & 15;

    // staging: slot = i*256 + tid; m = slot>>3; kc = slot&7 (linear)
    const u16* aSrc[4]; const u16* bSrc[4];
    u16* aDst[4]; u16* bDst[4];
#pragma unroll
    for (int i = 0; i < 4; ++i) {
        int slot = i * 256 + tid;
        int m = slot >> 3;
        int kc = slot & 7;
        aSrc[i] = A + (size_t)(row0 + m) * lda + kc * 8;
        bSrc[i] = Bt + (size_t)(n0 + m) * ldb + kc * 8;
        aDst[i] = As + slot * 8;
        bDst[i] = Bs + slot * 8;
    }

    f32x4 acc[4][4];
#pragma unroll
    for (int i = 0; i < 4; ++i)
#pragma unroll
        for (int j = 0; j < 4; ++j) acc[i][j] = f32x4{0.f, 0.f, 0.f, 0.f};

    for (int k0 = k_begin; k0 < k_end; k0 += 64) {
#pragma unroll
        for (int i = 0; i < 4; ++i) gload16(aDst[i], aSrc[i] + k0);
#pragma unroll
        for (int i = 0; i < 4; ++i) gload16(bDst[i], bSrc[i] + k0);
        asm volatile("s_waitcnt vmcnt(0)" ::: "memory");
        __syncthreads();
#pragma unroll
        for (int kk = 0; kk < 2; ++kk) {
            int kc = kk * 4 + kq;
            bf16x8 af[4], bfr[4];
#pragma unroll
            for (int i = 0; i < 4; ++i) {
                int rowA = wm * 64 + i * 16 + l15;
                af[i] = *(const bf16x8*)(As + rowA * 64 + kc * 8);
                int rowB = wn * 64 + i * 16 + l15;
                bfr[i] = *(const bf16x8*)(Bs + rowB * 64 + kc * 8);
            }
#pragma unroll
            for (int i = 0; i < 4; ++i)
#pragma unroll
                for (int j = 0; j < 4; ++j)
                    acc[i][j] = __builtin_amdgcn_mfma_f32_16x16x32_bf16(
                        af[i], bfr[j], acc[i][j], 0, 0, 0);
        }
        __syncthreads();
    }

    if constexpr (MODE == 0) {
        const float* b1e = b1 + (size_t)e * F_DIM;
#pragma unroll
        for (int i = 0; i < 4; ++i) {
            int gr = row0 + wm * 64 + i * 16 + kq * 4;
#pragma unroll
            for (int j = 0; j < 4; ++j) {
                int gc = n0 + wn * 64 + j * 16 + l15;
                float bb = b1e[gc];
#pragma unroll
                for (int r = 0; r < 4; ++r) {
                    float v = acc[i][j][r] + bb;
                    float h = 0.5f * v * (1.0f + erff(v * 0.70710678118f));
                    Hout[(size_t)(gr + r) * F_DIM + gc] = f2b(h);
                }
            }
        }
    } else {
#pragma unroll
        for (int i = 0; i < 4; ++i) {
            int grb = row0 + wm * 64 + i * 16 + kq * 4;
#pragma unroll
            for (int r = 0; r < 4; ++r) {
                int tok = rowmap[grb + r];
                float g = rowgate[grb + r];
                if (tok >= 0 && tok < T_TOK) {
                    float* orow = outacc + (size_t)tok * D_DIM;
#pragma unroll
                    for (int j = 0; j < 4; ++j) {
                        int gc = n0 + wn * 64 + j * 16 + l15;
                        atomicAdd(orow + gc, g * acc[i][j][r]);
                    }
                }
            }
        }
    }
}

// ---------------- final: out = outacc + g0*b2[i0] + g1*b2[i1] (fp32) --------
__global__ void final_k(const float* __restrict__ outacc, const int* __restrict__ idxs,
                        const float* __restrict__ gates, const float* __restrict__ b2,
                        float* __restrict__ dout) {
    int t = blockIdx.x;
    int i0 = min(max(idxs[t * 2], 0), E_EXP - 1);
    int i1 = min(max(idxs[t * 2 + 1], 0), E_EXP - 1);
    float g0 = gates[t * 2], g1 = gates[t * 2 + 1];
    int d = threadIdx.x * 2;
    float2 oa = *(const float2*)(outacc + (size_t)t * D_DIM + d);
    const float* p0 = b2 + (size_t)i0 * D_DIM + d;
    const float* p1 = b2 + (size_t)i1 * D_DIM + d;
    float2 o;
    o.x = oa.x + g0 * p0[0] + g1 * p1[0];
    o.y = oa.y + g0 * p0[1] + g1 * p1[1];
    *(float2*)(dout + (size_t)t * D_DIM + d) = o;
}

// ---------------- workspace layout (bytes) — total need ~86 MB --------------
#define OFF_AN      0u           // 16 KB fp32 a_n
#define OFF_CNT     0x10000u
#define OFF_OFFS    0x10100u
#define OFF_CUR     0x10200u
#define OFF_IDX     0x20000u     // int[T*2]
#define OFF_GATE    0x28000u     // float[T*2]
#define OFF_ROWMAP  0x30000u     // int[NROWS]
#define OFF_ROWGATE 0x40000u     // float[NROWS]
#define OFF_OUTACC  0x50000u     // 8 MB fp32[T*D]   -> ends 0x850000
#define OFF_XG      0x900000u    // 9.44 MB u16[NROWS*D]  -> ends 0x1200000
#define OFF_W1T     0x1200000u   // 16.78 MB u16[E][F][D] -> ends 0x2200000
#define OFF_W2T     0x2200000u   // 16.78 MB u16[E][D][F] -> ends 0x3200000
#define OFF_HG      0x3200000u   // 37.75 MB u16[NROWS*F] -> ends 0x5600000

extern "C" void kernel_launch(void* const* d_in, const int* in_sizes, int n_in,
                              void* d_out, int out_size, void* d_ws, size_t ws_size,
                              hipStream_t stream) {
    const float* x       = (const float*)d_in[0];
    const float* anchors = (const float*)d_in[1];
    const float* W1      = (const float*)d_in[2];
    const float* b1      = (const float*)d_in[3];
    const float* W2      = (const float*)d_in[4];
    const float* b2      = (const float*)d_in[5];
    float* out = (float*)d_out;

    char* ws = (char*)d_ws;
    float* an      = (float*)(ws + OFF_AN);
    int*   cnt     = (int*)(ws + OFF_CNT);
    int*   offs    = (int*)(ws + OFF_OFFS);
    int*   cur     = (int*)(ws + OFF_CUR);
    int*   idxs    = (int*)(ws + OFF_IDX);
    float* gates   = (float*)(ws + OFF_GATE);
    int*   rowmap  = (int*)(ws + OFF_ROWMAP);
    float* rowgate = (float*)(ws + OFF_ROWGATE);
    float* outacc  = (float*)(ws + OFF_OUTACC);
    u16*   Xg      = (u16*)(ws + OFF_XG);
    u16*   W1T     = (u16*)(ws + OFF_W1T);
    u16*   W2T     = (u16*)(ws + OFF_W2T);
    u16*   Hg      = (u16*)(ws + OFF_HG);

    // d_out sections (fp32 elements): out | a_n | scores | topk_idx
    float* out_main   = out;
    float* out_an     = out + (size_t)T_TOK * D_DIM;
    float* out_scores = out_an + E_EXP * D_DIM;
    float* out_idx    = out_scores + (size_t)T_TOK * E_EXP;

    hipMemsetAsync(cnt, 0, E_EXP * sizeof(int), stream);
    hipMemsetAsync(rowmap, 0xFF, NROWS * sizeof(int), stream);
    hipMemsetAsync(rowgate, 0, NROWS * sizeof(float), stream);
    hipMemsetAsync(outacc, 0, (size_t)T_TOK * D_DIM * sizeof(float), stream);

    anchors_k<<<1, 512, 0, stream>>>(anchors, an, out_an);
    routing_k<<<T_TOK / 64, 256, 0, stream>>>(x, an, out_scores, out_idx,
                                              idxs, gates, cnt);
    offs_k<<<1, 64, 0, stream>>>(cnt, offs, cur);
    assign_k<<<T_TOK / 256, 256, 0, stream>>>(idxs, gates, cur, rowmap, rowgate);
    gather_k<<<NROWS, 256, 0, stream>>>(x, rowmap, Xg);
    // W1 [E][D][F] -> W1T [E][F][D];  W2 [E][F][D] -> W2T [E][D][F]
    transpose_cast_k<<<dim3(F_DIM / 32, D_DIM / 32, E_EXP), dim3(32, 8), 0, stream>>>(
        W1, W1T, D_DIM, F_DIM);
    transpose_cast_k<<<dim3(D_DIM / 32, F_DIM / 32, E_EXP), dim3(32, 8), 0, stream>>>(
        W2, W2T, F_DIM, D_DIM);
    gemm_k<0><<<dim3(F_DIM / 128, MAXTILES, 1), 256, 0, stream>>>(
        Xg, D_DIM, W1T, D_DIM, Hg, b1, nullptr, rowmap, nullptr, offs, D_DIM);
    gemm_k<1><<<dim3(D_DIM / 128, MAXTILES, 2), 256, 0, stream>>>(
        Hg, F_DIM, W2T, F_DIM, nullptr, nullptr, outacc, rowmap, rowgate,
        offs, F_DIM / 2);
    final_k<<<T_TOK, 256, 0, stream>>>(outacc, idxs, gates, b2, out_main);
}

// Round 10
// 277.780 us; speedup vs baseline: 2.6705x; 1.0370x over previous
//
#include <hip/hip_runtime.h>
#include <cstdint>

// ---------------------------------------------------------------------------
// Round 10: three changes vs round 9 (288 µs):
//  1. gemm_k LDS XOR chunk swizzle (round-1-proven bijection) — kills the
//     6.68M-cycle SQ_LDS_BANK_CONFLICT (16-way quad aliasing in linear layout).
//  2. transpose_cast vectorized: 64x64 tile, float4 loads, ushort4 stores,
//     pad-65 scalar LDS (2-way max = free).
//  3. init_k replaces 4 hipMemsetAsync (17 -> 11 dispatches).
// ---------------------------------------------------------------------------

#define T_TOK 4096
#define D_DIM 512
#define F_DIM 2048
#define E_EXP 8
#define NROWS 9216      // 8192 assignments + 8*128 pad
#define MAXTILES 72     // NROWS / 128

typedef __bf16 bf16x8 __attribute__((ext_vector_type(8)));
typedef float  f32x4  __attribute__((ext_vector_type(4)));
typedef unsigned short u16;

__device__ __forceinline__ u16 f2b(float f) {
    return __builtin_bit_cast(unsigned short, (__bf16)f);
}
__device__ __forceinline__ void gload16(void* lds, const void* g) {
    __builtin_amdgcn_global_load_lds(
        (const __attribute__((address_space(1))) void*)g,
        (__attribute__((address_space(3))) void*)lds, 16, 0, 0);
}

// ---------------- init: cnt/rowmap/rowgate/outacc in ONE dispatch -----------
__global__ void init_k(int* __restrict__ cnt, int* __restrict__ rowmap,
                       float* __restrict__ rowgate, float* __restrict__ outacc) {
    int tid = blockIdx.x * 256 + threadIdx.x;
    int nth = gridDim.x * 256;
    if (tid < E_EXP) cnt[tid] = 0;
    for (int i = tid; i < NROWS; i += nth) { rowmap[i] = -1; rowgate[i] = 0.f; }
    float4* o4 = (float4*)outacc;
    for (int i = tid; i < (T_TOK * D_DIM) / 4; i += nth)
        o4[i] = float4{0.f, 0.f, 0.f, 0.f};
}

// ---------------- anchors: a_n = a / max(||a||, eps) ------------------------
__global__ void anchors_k(const float* __restrict__ anchors,
                          float* __restrict__ an, float* __restrict__ dout_an) {
    int tid = threadIdx.x;           // 512 threads = 8 waves, wave e = anchor e
    int lane = tid & 63, e = tid >> 6;
    const float4* ar = (const float4*)(anchors + e * D_DIM + lane * 8);
    float4 v0 = ar[0], v1 = ar[1];
    float ss = v0.x*v0.x + v0.y*v0.y + v0.z*v0.z + v0.w*v0.w
             + v1.x*v1.x + v1.y*v1.y + v1.z*v1.z + v1.w*v1.w;
#pragma unroll
    for (int off = 32; off >= 1; off >>= 1) ss += __shfl_xor(ss, off, 64);
    float inv = 1.0f / fmaxf(sqrtf(ss), 1e-8f);
    float o[8] = {v0.x*inv, v0.y*inv, v0.z*inv, v0.w*inv,
                  v1.x*inv, v1.y*inv, v1.z*inv, v1.w*inv};
#pragma unroll
    for (int i = 0; i < 8; ++i) {
        an[e * D_DIM + lane * 8 + i] = o[i];
        dout_an[e * D_DIM + lane * 8 + i] = o[i];
    }
}

// ---------------- routing: 4 threads per token ------------------------------
__global__ void routing_k(const float* __restrict__ x, const float* __restrict__ an,
                          float* __restrict__ dout_scores, float* __restrict__ dout_idx,
                          int* __restrict__ idxs, float* __restrict__ gates,
                          int* __restrict__ cnt) {
    __shared__ float anl[E_EXP * 544];   // [e][p*136 + i], i<128
    __shared__ int hist[E_EXP];
    int tid = threadIdx.x;
    if (tid < E_EXP) hist[tid] = 0;
    for (int i = tid; i < E_EXP * D_DIM; i += 256) {
        int e = i >> 9, d = i & 511;
        anl[e * 544 + (d >> 7) * 136 + (d & 127)] = an[i];
    }
    __syncthreads();

    int p = tid & 3;
    int tok = blockIdx.x * 64 + (tid >> 2);
    const float4* xr = (const float4*)(x + (size_t)tok * D_DIM + p * 128);
    const float* ab = &anl[p * 136];
    float dot[E_EXP] = {};
    float ss = 0.f;
    for (int c = 0; c < 32; ++c) {
        float4 xv = xr[c];
        ss += xv.x*xv.x + xv.y*xv.y + xv.z*xv.z + xv.w*xv.w;
#pragma unroll
        for (int e = 0; e < E_EXP; ++e) {
            float4 av = *(const float4*)&ab[e * 544 + c * 4];
            dot[e] += xv.x*av.x + xv.y*av.y + xv.z*av.z + xv.w*av.w;
        }
    }
#pragma unroll
    for (int off = 1; off <= 2; off <<= 1) {
        ss += __shfl_xor(ss, off, 64);
#pragma unroll
        for (int e = 0; e < E_EXP; ++e) dot[e] += __shfl_xor(dot[e], off, 64);
    }

    if (p == 0) {
        float inv = 1.0f / fmaxf(sqrtf(ss), 1e-8f);
        float s[E_EXP];
#pragma unroll
        for (int e = 0; e < E_EXP; ++e) s[e] = dot[e] * inv;
        int i0 = 0; float b0 = s[0];
#pragma unroll
        for (int e = 1; e < E_EXP; ++e) if (s[e] > b0) { b0 = s[e]; i0 = e; }
        int i1 = -1; float b1v = -1e30f;
#pragma unroll
        for (int e = 0; e < E_EXP; ++e)
            if (e != i0 && s[e] > b1v) { b1v = s[e]; i1 = e; }
        if (i1 < 0) { i1 = (i0 + 1) & 7; b1v = s[i1]; }   // NaN-safety
        float g0 = 1.0f / (1.0f + expf(b1v - b0));
        float g1 = 1.0f - g0;
#pragma unroll
        for (int e = 0; e < E_EXP; ++e) dout_scores[tok * E_EXP + e] = s[e];
        dout_idx[tok * 2 + 0] = (float)i0;
        dout_idx[tok * 2 + 1] = (float)i1;
        idxs[tok * 2 + 0] = i0; idxs[tok * 2 + 1] = i1;
        gates[tok * 2 + 0] = g0; gates[tok * 2 + 1] = g1;
        atomicAdd(&hist[i0], 1);
        atomicAdd(&hist[i1], 1);
    }
    __syncthreads();
    if (tid < E_EXP) atomicAdd(&cnt[tid], hist[tid]);
}

// ---------------- offsets (128-padded) + cursors ----------------------------
__global__ void offs_k(const int* __restrict__ cnt, int* __restrict__ offs,
                       int* __restrict__ cur) {
    if (threadIdx.x == 0 && blockIdx.x == 0) {
        int acc = 0;
        for (int e = 0; e < E_EXP; ++e) {
            offs[e] = acc; cur[e] = acc;
            acc += (cnt[e] + 127) & ~127;
        }
        offs[E_EXP] = acc;
    }
}

// ---------------- slot assignment (bounds-clamped) --------------------------
__global__ void assign_k(const int* __restrict__ idxs, const float* __restrict__ gates,
                         int* __restrict__ cur, int* __restrict__ rowmap,
                         float* __restrict__ rowgate) {
    int t = blockIdx.x * 256 + threadIdx.x;
    if (t >= T_TOK) return;
#pragma unroll
    for (int k = 0; k < 2; ++k) {
        int e = idxs[t * 2 + k];
        e = min(max(e, 0), E_EXP - 1);
        int r = atomicAdd(&cur[e], 1);
        if (r >= 0 && r < NROWS) {
            rowmap[r] = t;
            rowgate[r] = gates[t * 2 + k];
        }
    }
}

// ---------------- gather tokens -> bf16 rows (pad rows zeroed) --------------
__global__ void gather_k(const float* __restrict__ x, const int* __restrict__ rowmap,
                         u16* __restrict__ Xg) {
    int r = blockIdx.x;
    int t = rowmap[r];
    int c = threadIdx.x * 2;     // 256 threads x 2 = 512 elems
    ushort2 o;
    if (t < 0 || t >= T_TOK) { o.x = 0; o.y = 0; }
    else {
        float2 v = *(const float2*)(x + (size_t)t * D_DIM + c);
        o.x = f2b(v.x); o.y = f2b(v.y);
    }
    *(ushort2*)(Xg + (size_t)r * D_DIM + c) = o;
}

// ---------------- transpose+cast fp32 [Z][R][C] -> bf16 [Z][C][R] -----------
// 64x64 tile, 256 threads; float4 coalesced loads, ushort4 coalesced stores,
// scalar LDS with pad 65 (2-way bank max = free).
__global__ void transpose_cast_k(const float* __restrict__ in, u16* __restrict__ out,
                                 int R, int C) {
    size_t zoff = (size_t)blockIdx.z * R * C;
    in += zoff; out += zoff;
    __shared__ float t[64][65];
    int c0 = blockIdx.x * 64, r0 = blockIdx.y * 64;
    int tid = threadIdx.x;
    int cq = tid & 15, rb = tid >> 4;
#pragma unroll
    for (int pass = 0; pass < 4; ++pass) {
        int rr = rb + pass * 16;
        float4 v = *(const float4*)(in + (size_t)(r0 + rr) * C + c0 + cq * 4);
        t[rr][cq * 4 + 0] = v.x; t[rr][cq * 4 + 1] = v.y;
        t[rr][cq * 4 + 2] = v.z; t[rr][cq * 4 + 3] = v.w;
    }
    __syncthreads();
    int rg = tid & 15, cb = tid >> 4;
#pragma unroll
    for (int pass = 0; pass < 4; ++pass) {
        int c = cb + pass * 16;
        ushort4 o;
        o.x = f2b(t[rg * 4 + 0][c]); o.y = f2b(t[rg * 4 + 1][c]);
        o.z = f2b(t[rg * 4 + 2][c]); o.w = f2b(t[rg * 4 + 3][c]);
        *(ushort4*)(out + (size_t)(c0 + c) * R + r0 + rg * 4) = o;
    }
}

// ---------------- grouped GEMM core -----------------------------------------
// MODE 0: Hg = bf16(gelu(Xg @ W1e^T + b1e))   (N=F, K=D)
// MODE 1: outacc[tok] += gate * (Hg @ W2e^T)  (N=D, K=F, split-K via blockIdx.z)
// LDS: XOR-swizzled chunks — chunk (m, kc) (8 bf16 = 16B) stored at physical
// slot m*8 + (kc ^ (m&7)). Fragment reads tile all 32 banks 2-way (free).
template <int MODE>
__launch_bounds__(256, 2)
__global__ void gemm_k(const u16* __restrict__ A, int lda,
                       const u16* __restrict__ BtBase, int ldb,
                       u16* __restrict__ Hout, const float* __restrict__ b1,
                       float* __restrict__ outacc,
                       const int* __restrict__ rowmap, const float* __restrict__ rowgate,
                       const int* __restrict__ offs, int kPer) {
    int row0 = blockIdx.y * 128;
    if (row0 >= offs[E_EXP]) return;
    int e = 0;
#pragma unroll
    for (int i = 1; i < E_EXP; ++i) if (row0 >= offs[i]) e = i;
    const u16* Bt = BtBase + (size_t)e * D_DIM * F_DIM;
    int n0 = blockIdx.x * 128;
    int k_begin = (MODE == 1) ? (int)blockIdx.z * kPer : 0;
    int k_end = k_begin + kPer;

    alignas(16) __shared__ u16 As[128 * 64];
    alignas(16) __shared__ u16 Bs[128 * 64];

    int tid = threadIdx.x;
    int lane = tid & 63;
    int wv = tid >> 6;
    int wm = wv & 1, wn = wv >> 1;
    int kq = lane >> 4;          // quad 0..3
    int l15 = lane & 15;

    // staging: slot = i*256 + tid; m = slot>>3; logical kc = (slot&7)^(m&7)
    const u16* aSrc[4]; const u16* bSrc[4];
    u16* aDst[4]; u16* bDst[4];
#pragma unroll
    for (int i = 0; i < 4; ++i) {
        int slot = i * 256 + tid;
        int m = slot >> 3;
        int kc = (slot & 7) ^ (m & 7);
        aSrc[i] = A + (size_t)(row0 + m) * lda + kc * 8;
        bSrc[i] = Bt + (size_t)(n0 + m) * ldb + kc * 8;
        aDst[i] = As + slot * 8;
        bDst[i] = Bs + slot * 8;
    }

    f32x4 acc[4][4];
#pragma unroll
    for (int i = 0; i < 4; ++i)
#pragma unroll
        for (int j = 0; j < 4; ++j) acc[i][j] = f32x4{0.f, 0.f, 0.f, 0.f};

    for (int k0 = k_begin; k0 < k_end; k0 += 64) {
#pragma unroll
        for (int i = 0; i < 4; ++i) gload16(aDst[i], aSrc[i] + k0);
#pragma unroll
        for (int i = 0; i < 4; ++i) gload16(bDst[i], bSrc[i] + k0);
        asm volatile("s_waitcnt vmcnt(0)" ::: "memory");
        __syncthreads();
#pragma unroll
        for (int kk = 0; kk < 2; ++kk) {
            int kc = kk * 4 + kq;
            bf16x8 af[4], bfr[4];
#pragma unroll
            for (int i = 0; i < 4; ++i) {
                int rowA = wm * 64 + i * 16 + l15;
                af[i] = *(const bf16x8*)(As + rowA * 64 + ((kc ^ (rowA & 7)) * 8));
                int rowB = wn * 64 + i * 16 + l15;
                bfr[i] = *(const bf16x8*)(Bs + rowB * 64 + ((kc ^ (rowB & 7)) * 8));
            }
#pragma unroll
            for (int i = 0; i < 4; ++i)
#pragma unroll
                for (int j = 0; j < 4; ++j)
                    acc[i][j] = __builtin_amdgcn_mfma_f32_16x16x32_bf16(
                        af[i], bfr[j], acc[i][j], 0, 0, 0);
        }
        __syncthreads();
    }

    if constexpr (MODE == 0) {
        const float* b1e = b1 + (size_t)e * F_DIM;
#pragma unroll
        for (int i = 0; i < 4; ++i) {
            int gr = row0 + wm * 64 + i * 16 + kq * 4;
#pragma unroll
            for (int j = 0; j < 4; ++j) {
                int gc = n0 + wn * 64 + j * 16 + l15;
                float bb = b1e[gc];
#pragma unroll
                for (int r = 0; r < 4; ++r) {
                    float v = acc[i][j][r] + bb;
                    float h = 0.5f * v * (1.0f + erff(v * 0.70710678118f));
                    Hout[(size_t)(gr + r) * F_DIM + gc] = f2b(h);
                }
            }
        }
    } else {
#pragma unroll
        for (int i = 0; i < 4; ++i) {
            int grb = row0 + wm * 64 + i * 16 + kq * 4;
#pragma unroll
            for (int r = 0; r < 4; ++r) {
                int tok = rowmap[grb + r];
                float g = rowgate[grb + r];
                if (tok >= 0 && tok < T_TOK) {
                    float* orow = outacc + (size_t)tok * D_DIM;
#pragma unroll
                    for (int j = 0; j < 4; ++j) {
                        int gc = n0 + wn * 64 + j * 16 + l15;
                        atomicAdd(orow + gc, g * acc[i][j][r]);
                    }
                }
            }
        }
    }
}

// ---------------- final: out = outacc + g0*b2[i0] + g1*b2[i1] (fp32) --------
__global__ void final_k(const float* __restrict__ outacc, const int* __restrict__ idxs,
                        const float* __restrict__ gates, const float* __restrict__ b2,
                        float* __restrict__ dout) {
    int t = blockIdx.x;
    int i0 = min(max(idxs[t * 2], 0), E_EXP - 1);
    int i1 = min(max(idxs[t * 2 + 1], 0), E_EXP - 1);
    float g0 = gates[t * 2], g1 = gates[t * 2 + 1];
    int d = threadIdx.x * 2;
    float2 oa = *(const float2*)(outacc + (size_t)t * D_DIM + d);
    const float* p0 = b2 + (size_t)i0 * D_DIM + d;
    const float* p1 = b2 + (size_t)i1 * D_DIM + d;
    float2 o;
    o.x = oa.x + g0 * p0[0] + g1 * p1[0];
    o.y = oa.y + g0 * p0[1] + g1 * p1[1];
    *(float2*)(dout + (size_t)t * D_DIM + d) = o;
}

// ---------------- workspace layout (bytes) — total need ~86 MB --------------
#define OFF_AN      0u           // 16 KB fp32 a_n
#define OFF_CNT     0x10000u
#define OFF_OFFS    0x10100u
#define OFF_CUR     0x10200u
#define OFF_IDX     0x20000u     // int[T*2]
#define OFF_GATE    0x28000u     // float[T*2]
#define OFF_ROWMAP  0x30000u     // int[NROWS]
#define OFF_ROWGATE 0x40000u     // float[NROWS]
#define OFF_OUTACC  0x50000u     // 8 MB fp32[T*D]   -> ends 0x850000
#define OFF_XG      0x900000u    // 9.44 MB u16[NROWS*D]  -> ends 0x1200000
#define OFF_W1T     0x1200000u   // 16.78 MB u16[E][F][D] -> ends 0x2200000
#define OFF_W2T     0x2200000u   // 16.78 MB u16[E][D][F] -> ends 0x3200000
#define OFF_HG      0x3200000u   // 37.75 MB u16[NROWS*F] -> ends 0x5600000

extern "C" void kernel_launch(void* const* d_in, const int* in_sizes, int n_in,
                              void* d_out, int out_size, void* d_ws, size_t ws_size,
                              hipStream_t stream) {
    const float* x       = (const float*)d_in[0];
    const float* anchors = (const float*)d_in[1];
    const float* W1      = (const float*)d_in[2];
    const float* b1      = (const float*)d_in[3];
    const float* W2      = (const float*)d_in[4];
    const float* b2      = (const float*)d_in[5];
    float* out = (float*)d_out;

    char* ws = (char*)d_ws;
    float* an      = (float*)(ws + OFF_AN);
    int*   cnt     = (int*)(ws + OFF_CNT);
    int*   offs    = (int*)(ws + OFF_OFFS);
    int*   cur     = (int*)(ws + OFF_CUR);
    int*   idxs    = (int*)(ws + OFF_IDX);
    float* gates   = (float*)(ws + OFF_GATE);
    int*   rowmap  = (int*)(ws + OFF_ROWMAP);
    float* rowgate = (float*)(ws + OFF_ROWGATE);
    float* outacc  = (float*)(ws + OFF_OUTACC);
    u16*   Xg      = (u16*)(ws + OFF_XG);
    u16*   W1T     = (u16*)(ws + OFF_W1T);
    u16*   W2T     = (u16*)(ws + OFF_W2T);
    u16*   Hg      = (u16*)(ws + OFF_HG);

    // d_out sections (fp32 elements): out | a_n | scores | topk_idx
    float* out_main   = out;
    float* out_an     = out + (size_t)T_TOK * D_DIM;
    float* out_scores = out_an + E_EXP * D_DIM;
    float* out_idx    = out_scores + (size_t)T_TOK * E_EXP;

    init_k<<<512, 256, 0, stream>>>(cnt, rowmap, rowgate, outacc);
    anchors_k<<<1, 512, 0, stream>>>(anchors, an, out_an);
    routing_k<<<T_TOK / 64, 256, 0, stream>>>(x, an, out_scores, out_idx,
                                              idxs, gates, cnt);
    offs_k<<<1, 64, 0, stream>>>(cnt, offs, cur);
    assign_k<<<T_TOK / 256, 256, 0, stream>>>(idxs, gates, cur, rowmap, rowgate);
    gather_k<<<NROWS, 256, 0, stream>>>(x, rowmap, Xg);
    // W1 [E][D][F] -> W1T [E][F][D];  W2 [E][F][D] -> W2T [E][D][F]
    transpose_cast_k<<<dim3(F_DIM / 64, D_DIM / 64, E_EXP), 256, 0, stream>>>(
        W1, W1T, D_DIM, F_DIM);
    transpose_cast_k<<<dim3(D_DIM / 64, F_DIM / 64, E_EXP), 256, 0, stream>>>(
        W2, W2T, F_DIM, D_DIM);
    gemm_k<0><<<dim3(F_DIM / 128, MAXTILES, 1), 256, 0, stream>>>(
        Xg, D_DIM, W1T, D_DIM, Hg, b1, nullptr, rowmap, nullptr, offs, D_DIM);
    gemm_k<1><<<dim3(D_DIM / 128, MAXTILES, 2), 256, 0, stream>>>(
        Hg, F_DIM, W2T, F_DIM, nullptr, nullptr, outacc, rowmap, rowgate,
        offs, F_DIM / 2);
    final_k<<<T_TOK, 256, 0, stream>>>(outacc, idxs, gates, b2, out_main);
}

// Round 11
// 277.752 us; speedup vs baseline: 2.6707x; 1.0001x over previous
//
#include <hip/hip_runtime.h>
#include <cstdint>

// ---------------------------------------------------------------------------
// Round 11 vs round 10 (277.8 µs):
//  1. REVERT gemm LDS to linear [m][kc] (r9-proven): XOR swizzle killed bank
//     conflicts but non-affine ds_read addressing cost 4x VALU (59->77 µs).
//  2. GELU epilogue: erff -> tanh-approx via one __expf (err ~3e-4, << bf16).
//  3. final_k fused into gemm2 epilogue (atomicAdd g*(acc+b2[e]) into d_out,
//     bias on z==0 split only); init_k zeroes out_main. 10 dispatches.
// ---------------------------------------------------------------------------

#define T_TOK 4096
#define D_DIM 512
#define F_DIM 2048
#define E_EXP 8
#define NROWS 9216      // 8192 assignments + 8*128 pad
#define MAXTILES 72     // NROWS / 128

typedef __bf16 bf16x8 __attribute__((ext_vector_type(8)));
typedef float  f32x4  __attribute__((ext_vector_type(4)));
typedef unsigned short u16;

__device__ __forceinline__ u16 f2b(float f) {
    return __builtin_bit_cast(unsigned short, (__bf16)f);
}
__device__ __forceinline__ void gload16(void* lds, const void* g) {
    __builtin_amdgcn_global_load_lds(
        (const __attribute__((address_space(1))) void*)g,
        (__attribute__((address_space(3))) void*)lds, 16, 0, 0);
}
// tanh-approx GELU (jax approximate=True form; |err vs exact| ~3e-4 << bf16 ulp)
__device__ __forceinline__ float gelu_f(float v) {
    float z = 0.7978845608f * (v + 0.044715f * v * v * v);
    float t = 1.0f - 2.0f / (1.0f + __expf(2.0f * z));
    return 0.5f * v * (1.0f + t);
}

// ---------------- init: cnt/rowmap/rowgate/out_main in ONE dispatch ---------
__global__ void init_k(int* __restrict__ cnt, int* __restrict__ rowmap,
                       float* __restrict__ rowgate, float* __restrict__ outm) {
    int tid = blockIdx.x * 256 + threadIdx.x;
    int nth = gridDim.x * 256;
    if (tid < E_EXP) cnt[tid] = 0;
    for (int i = tid; i < NROWS; i += nth) { rowmap[i] = -1; rowgate[i] = 0.f; }
    float4* o4 = (float4*)outm;
    for (int i = tid; i < (T_TOK * D_DIM) / 4; i += nth)
        o4[i] = float4{0.f, 0.f, 0.f, 0.f};
}

// ---------------- anchors: a_n = a / max(||a||, eps) ------------------------
__global__ void anchors_k(const float* __restrict__ anchors,
                          float* __restrict__ an, float* __restrict__ dout_an) {
    int tid = threadIdx.x;           // 512 threads = 8 waves, wave e = anchor e
    int lane = tid & 63, e = tid >> 6;
    const float4* ar = (const float4*)(anchors + e * D_DIM + lane * 8);
    float4 v0 = ar[0], v1 = ar[1];
    float ss = v0.x*v0.x + v0.y*v0.y + v0.z*v0.z + v0.w*v0.w
             + v1.x*v1.x + v1.y*v1.y + v1.z*v1.z + v1.w*v1.w;
#pragma unroll
    for (int off = 32; off >= 1; off >>= 1) ss += __shfl_xor(ss, off, 64);
    float inv = 1.0f / fmaxf(sqrtf(ss), 1e-8f);
    float o[8] = {v0.x*inv, v0.y*inv, v0.z*inv, v0.w*inv,
                  v1.x*inv, v1.y*inv, v1.z*inv, v1.w*inv};
#pragma unroll
    for (int i = 0; i < 8; ++i) {
        an[e * D_DIM + lane * 8 + i] = o[i];
        dout_an[e * D_DIM + lane * 8 + i] = o[i];
    }
}

// ---------------- routing: 4 threads per token ------------------------------
__global__ void routing_k(const float* __restrict__ x, const float* __restrict__ an,
                          float* __restrict__ dout_scores, float* __restrict__ dout_idx,
                          int* __restrict__ idxs, float* __restrict__ gates,
                          int* __restrict__ cnt) {
    __shared__ float anl[E_EXP * 544];   // [e][p*136 + i], i<128
    __shared__ int hist[E_EXP];
    int tid = threadIdx.x;
    if (tid < E_EXP) hist[tid] = 0;
    for (int i = tid; i < E_EXP * D_DIM; i += 256) {
        int e = i >> 9, d = i & 511;
        anl[e * 544 + (d >> 7) * 136 + (d & 127)] = an[i];
    }
    __syncthreads();

    int p = tid & 3;
    int tok = blockIdx.x * 64 + (tid >> 2);
    const float4* xr = (const float4*)(x + (size_t)tok * D_DIM + p * 128);
    const float* ab = &anl[p * 136];
    float dot[E_EXP] = {};
    float ss = 0.f;
    for (int c = 0; c < 32; ++c) {
        float4 xv = xr[c];
        ss += xv.x*xv.x + xv.y*xv.y + xv.z*xv.z + xv.w*xv.w;
#pragma unroll
        for (int e = 0; e < E_EXP; ++e) {
            float4 av = *(const float4*)&ab[e * 544 + c * 4];
            dot[e] += xv.x*av.x + xv.y*av.y + xv.z*av.z + xv.w*av.w;
        }
    }
#pragma unroll
    for (int off = 1; off <= 2; off <<= 1) {
        ss += __shfl_xor(ss, off, 64);
#pragma unroll
        for (int e = 0; e < E_EXP; ++e) dot[e] += __shfl_xor(dot[e], off, 64);
    }

    if (p == 0) {
        float inv = 1.0f / fmaxf(sqrtf(ss), 1e-8f);
        float s[E_EXP];
#pragma unroll
        for (int e = 0; e < E_EXP; ++e) s[e] = dot[e] * inv;
        int i0 = 0; float b0 = s[0];
#pragma unroll
        for (int e = 1; e < E_EXP; ++e) if (s[e] > b0) { b0 = s[e]; i0 = e; }
        int i1 = -1; float b1v = -1e30f;
#pragma unroll
        for (int e = 0; e < E_EXP; ++e)
            if (e != i0 && s[e] > b1v) { b1v = s[e]; i1 = e; }
        if (i1 < 0) { i1 = (i0 + 1) & 7; b1v = s[i1]; }   // NaN-safety
        float g0 = 1.0f / (1.0f + expf(b1v - b0));
        float g1 = 1.0f - g0;
#pragma unroll
        for (int e = 0; e < E_EXP; ++e) dout_scores[tok * E_EXP + e] = s[e];
        dout_idx[tok * 2 + 0] = (float)i0;
        dout_idx[tok * 2 + 1] = (float)i1;
        idxs[tok * 2 + 0] = i0; idxs[tok * 2 + 1] = i1;
        gates[tok * 2 + 0] = g0; gates[tok * 2 + 1] = g1;
        atomicAdd(&hist[i0], 1);
        atomicAdd(&hist[i1], 1);
    }
    __syncthreads();
    if (tid < E_EXP) atomicAdd(&cnt[tid], hist[tid]);
}

// ---------------- offsets (128-padded) + cursors ----------------------------
__global__ void offs_k(const int* __restrict__ cnt, int* __restrict__ offs,
                       int* __restrict__ cur) {
    if (threadIdx.x == 0 && blockIdx.x == 0) {
        int acc = 0;
        for (int e = 0; e < E_EXP; ++e) {
            offs[e] = acc; cur[e] = acc;
            acc += (cnt[e] + 127) & ~127;
        }
        offs[E_EXP] = acc;
    }
}

// ---------------- slot assignment (bounds-clamped) --------------------------
__global__ void assign_k(const int* __restrict__ idxs, const float* __restrict__ gates,
                         int* __restrict__ cur, int* __restrict__ rowmap,
                         float* __restrict__ rowgate) {
    int t = blockIdx.x * 256 + threadIdx.x;
    if (t >= T_TOK) return;
#pragma unroll
    for (int k = 0; k < 2; ++k) {
        int e = idxs[t * 2 + k];
        e = min(max(e, 0), E_EXP - 1);
        int r = atomicAdd(&cur[e], 1);
        if (r >= 0 && r < NROWS) {
            rowmap[r] = t;
            rowgate[r] = gates[t * 2 + k];
        }
    }
}

// ---------------- gather tokens -> bf16 rows (pad rows zeroed) --------------
__global__ void gather_k(const float* __restrict__ x, const int* __restrict__ rowmap,
                         u16* __restrict__ Xg) {
    int r = blockIdx.x;
    int t = rowmap[r];
    int c = threadIdx.x * 2;     // 256 threads x 2 = 512 elems
    ushort2 o;
    if (t < 0 || t >= T_TOK) { o.x = 0; o.y = 0; }
    else {
        float2 v = *(const float2*)(x + (size_t)t * D_DIM + c);
        o.x = f2b(v.x); o.y = f2b(v.y);
    }
    *(ushort2*)(Xg + (size_t)r * D_DIM + c) = o;
}

// ---------------- transpose+cast fp32 [Z][R][C] -> bf16 [Z][C][R] -----------
__global__ void transpose_cast_k(const float* __restrict__ in, u16* __restrict__ out,
                                 int R, int C) {
    size_t zoff = (size_t)blockIdx.z * R * C;
    in += zoff; out += zoff;
    __shared__ float t[64][65];
    int c0 = blockIdx.x * 64, r0 = blockIdx.y * 64;
    int tid = threadIdx.x;
    int cq = tid & 15, rb = tid >> 4;
#pragma unroll
    for (int pass = 0; pass < 4; ++pass) {
        int rr = rb + pass * 16;
        float4 v = *(const float4*)(in + (size_t)(r0 + rr) * C + c0 + cq * 4);
        t[rr][cq * 4 + 0] = v.x; t[rr][cq * 4 + 1] = v.y;
        t[rr][cq * 4 + 2] = v.z; t[rr][cq * 4 + 3] = v.w;
    }
    __syncthreads();
    int rg = tid & 15, cb = tid >> 4;
#pragma unroll
    for (int pass = 0; pass < 4; ++pass) {
        int c = cb + pass * 16;
        ushort4 o;
        o.x = f2b(t[rg * 4 + 0][c]); o.y = f2b(t[rg * 4 + 1][c]);
        o.z = f2b(t[rg * 4 + 2][c]); o.w = f2b(t[rg * 4 + 3][c]);
        *(ushort4*)(out + (size_t)(c0 + c) * R + r0 + rg * 4) = o;
    }
}

// ---------------- grouped GEMM core (linear LDS, r9-proven) -----------------
// MODE 0: Hg = bf16(gelu(Xg @ W1e^T + b1e))         (N=F, K=D)
// MODE 1: out[tok] += gate*(Hg @ W2e^T + [z==0]b2e) (N=D, K=F, split-K=2)
// LDS: linear [m][kc], chunk (m,kc) (8 bf16 = 16B) at slot m*8+kc.
template <int MODE>
__launch_bounds__(256, 2)
__global__ void gemm_k(const u16* __restrict__ A, int lda,
                       const u16* __restrict__ BtBase, int ldb,
                       u16* __restrict__ Hout, const float* __restrict__ b1,
                       float* __restrict__ outm, const float* __restrict__ b2,
                       const int* __restrict__ rowmap, const float* __restrict__ rowgate,
                       const int* __restrict__ offs, int kPer) {
    int row0 = blockIdx.y * 128;
    if (row0 >= offs[E_EXP]) return;
    int e = 0;
#pragma unroll
    for (int i = 1; i < E_EXP; ++i) if (row0 >= offs[i]) e = i;
    const u16* Bt = BtBase + (size_t)e * D_DIM * F_DIM;
    int n0 = blockIdx.x * 128;
    int k_begin = (MODE == 1) ? (int)blockIdx.z * kPer : 0;
    int k_end = k_begin + kPer;

    alignas(16) __shared__ u16 As[128 * 64];
    alignas(16) __shared__ u16 Bs[128 * 64];

    int tid = threadIdx.x;
    int lane = tid & 63;
    int wv = tid >> 6;
    int wm = wv & 1, wn = wv >> 1;
    int kq = lane >> 4;          // quad 0..3
    int l15 = lane & 15;

    // staging: slot = i*256 + tid; m = slot>>3; kc = slot&7 (linear)
    const u16* aSrc[4]; const u16* bSrc[4];
    u16* aDst[4]; u16* bDst[4];
#pragma unroll
    for (int i = 0; i < 4; ++i) {
        int slot = i * 256 + tid;
        int m = slot >> 3;
        int kc = slot & 7;
        aSrc[i] = A + (size_t)(row0 + m) * lda + kc * 8;
        bSrc[i] = Bt + (size_t)(n0 + m) * ldb + kc * 8;
        aDst[i] = As + slot * 8;
        bDst[i] = Bs + slot * 8;
    }

    f32x4 acc[4][4];
#pragma unroll
    for (int i = 0; i < 4; ++i)
#pragma unroll
        for (int j = 0; j < 4; ++j) acc[i][j] = f32x4{0.f, 0.f, 0.f, 0.f};

    for (int k0 = k_begin; k0 < k_end; k0 += 64) {
#pragma unroll
        for (int i = 0; i < 4; ++i) gload16(aDst[i], aSrc[i] + k0);
#pragma unroll
        for (int i = 0; i < 4; ++i) gload16(bDst[i], bSrc[i] + k0);
        asm volatile("s_waitcnt vmcnt(0)" ::: "memory");
        __syncthreads();
#pragma unroll
        for (int kk = 0; kk < 2; ++kk) {
            int kc = kk * 4 + kq;
            bf16x8 af[4], bfr[4];
#pragma unroll
            for (int i = 0; i < 4; ++i) {
                int rowA = wm * 64 + i * 16 + l15;
                af[i] = *(const bf16x8*)(As + rowA * 64 + kc * 8);
                int rowB = wn * 64 + i * 16 + l15;
                bfr[i] = *(const bf16x8*)(Bs + rowB * 64 + kc * 8);
            }
#pragma unroll
            for (int i = 0; i < 4; ++i)
#pragma unroll
                for (int j = 0; j < 4; ++j)
                    acc[i][j] = __builtin_amdgcn_mfma_f32_16x16x32_bf16(
                        af[i], bfr[j], acc[i][j], 0, 0, 0);
        }
        __syncthreads();
    }

    if constexpr (MODE == 0) {
        const float* b1e = b1 + (size_t)e * F_DIM;
#pragma unroll
        for (int i = 0; i < 4; ++i) {
            int gr = row0 + wm * 64 + i * 16 + kq * 4;
#pragma unroll
            for (int j = 0; j < 4; ++j) {
                int gc = n0 + wn * 64 + j * 16 + l15;
                float bb = b1e[gc];
#pragma unroll
                for (int r = 0; r < 4; ++r) {
                    float v = acc[i][j][r] + bb;
                    Hout[(size_t)(gr + r) * F_DIM + gc] = f2b(gelu_f(v));
                }
            }
        }
    } else {
        const float* b2e = b2 + (size_t)e * D_DIM;
        bool addBias = (k_begin == 0);
#pragma unroll
        for (int i = 0; i < 4; ++i) {
            int grb = row0 + wm * 64 + i * 16 + kq * 4;
#pragma unroll
            for (int r = 0; r < 4; ++r) {
                int tok = rowmap[grb + r];
                float g = rowgate[grb + r];
                if (tok >= 0 && tok < T_TOK) {
                    float* orow = outm + (size_t)tok * D_DIM;
#pragma unroll
                    for (int j = 0; j < 4; ++j) {
                        int gc = n0 + wn * 64 + j * 16 + l15;
                        float bb = addBias ? b2e[gc] : 0.f;
                        atomicAdd(orow + gc, g * (acc[i][j][r] + bb));
                    }
                }
            }
        }
    }
}

// ---------------- workspace layout (bytes) — total need ~81 MB --------------
#define OFF_AN      0u           // 16 KB fp32 a_n
#define OFF_CNT     0x10000u
#define OFF_OFFS    0x10100u
#define OFF_CUR     0x10200u
#define OFF_IDX     0x20000u     // int[T*2]
#define OFF_GATE    0x28000u     // float[T*2]
#define OFF_ROWMAP  0x30000u     // int[NROWS]
#define OFF_ROWGATE 0x40000u     // float[NROWS]
#define OFF_XG      0x900000u    // 9.44 MB u16[NROWS*D]  -> ends 0x1200000
#define OFF_W1T     0x1200000u   // 16.78 MB u16[E][F][D] -> ends 0x2200000
#define OFF_W2T     0x2200000u   // 16.78 MB u16[E][D][F] -> ends 0x3200000
#define OFF_HG      0x3200000u   // 37.75 MB u16[NROWS*F] -> ends 0x5600000

extern "C" void kernel_launch(void* const* d_in, const int* in_sizes, int n_in,
                              void* d_out, int out_size, void* d_ws, size_t ws_size,
                              hipStream_t stream) {
    const float* x       = (const float*)d_in[0];
    const float* anchors = (const float*)d_in[1];
    const float* W1      = (const float*)d_in[2];
    const float* b1      = (const float*)d_in[3];
    const float* W2      = (const float*)d_in[4];
    const float* b2      = (const float*)d_in[5];
    float* out = (float*)d_out;

    char* ws = (char*)d_ws;
    float* an      = (float*)(ws + OFF_AN);
    int*   cnt     = (int*)(ws + OFF_CNT);
    int*   offs    = (int*)(ws + OFF_OFFS);
    int*   cur     = (int*)(ws + OFF_CUR);
    int*   idxs    = (int*)(ws + OFF_IDX);
    float* gates   = (float*)(ws + OFF_GATE);
    int*   rowmap  = (int*)(ws + OFF_ROWMAP);
    float* rowgate = (float*)(ws + OFF_ROWGATE);
    u16*   Xg      = (u16*)(ws + OFF_XG);
    u16*   W1T     = (u16*)(ws + OFF_W1T);
    u16*   W2T     = (u16*)(ws + OFF_W2T);
    u16*   Hg      = (u16*)(ws + OFF_HG);

    // d_out sections (fp32 elements): out | a_n | scores | topk_idx
    float* out_main   = out;
    float* out_an     = out + (size_t)T_TOK * D_DIM;
    float* out_scores = out_an + E_EXP * D_DIM;
    float* out_idx    = out_scores + (size_t)T_TOK * E_EXP;

    init_k<<<512, 256, 0, stream>>>(cnt, rowmap, rowgate, out_main);
    anchors_k<<<1, 512, 0, stream>>>(anchors, an, out_an);
    routing_k<<<T_TOK / 64, 256, 0, stream>>>(x, an, out_scores, out_idx,
                                              idxs, gates, cnt);
    offs_k<<<1, 64, 0, stream>>>(cnt, offs, cur);
    assign_k<<<T_TOK / 256, 256, 0, stream>>>(idxs, gates, cur, rowmap, rowgate);
    gather_k<<<NROWS, 256, 0, stream>>>(x, rowmap, Xg);
    // W1 [E][D][F] -> W1T [E][F][D];  W2 [E][F][D] -> W2T [E][D][F]
    transpose_cast_k<<<dim3(F_DIM / 64, D_DIM / 64, E_EXP), 256, 0, stream>>>(
        W1, W1T, D_DIM, F_DIM);
    transpose_cast_k<<<dim3(D_DIM / 64, F_DIM / 64, E_EXP), 256, 0, stream>>>(
        W2, W2T, F_DIM, D_DIM);
    gemm_k<0><<<dim3(F_DIM / 128, MAXTILES, 1), 256, 0, stream>>>(
        Xg, D_DIM, W1T, D_DIM, Hg, b1, nullptr, nullptr,
        rowmap, nullptr, offs, D_DIM);
    gemm_k<1><<<dim3(D_DIM / 128, MAXTILES, 2), 256, 0, stream>>>(
        Hg, F_DIM, W2T, F_DIM, nullptr, nullptr, out_main, b2,
        rowmap, rowgate, offs, F_DIM / 2);
}

// Round 12
// 276.113 us; speedup vs baseline: 2.6866x; 1.0059x over previous
//
#include <hip/hip_runtime.h>
#include <cstdint>

// ---------------------------------------------------------------------------
// Round 12 vs round 11 (277.8 µs): attack gemm stalls (nothing saturated:
// Mfma 10%, VALU 7%, HBM 23%, occ 20%).
//  1. __launch_bounds__(256,4): 2 -> 4 blocks/CU (barrier-drain overlap).
//  2. XCD-locality swizzle: 1D grid, tile = (L%8)*(total/8)+L/8 -> each XCD
//     L2 owns a contiguous m-tile range (FETCH 86.7MB -> ~40MB predicted).
// ---------------------------------------------------------------------------

#define T_TOK 4096
#define D_DIM 512
#define F_DIM 2048
#define E_EXP 8
#define NROWS 9216      // 8192 assignments + 8*128 pad
#define MAXTILES 72     // NROWS / 128

typedef __bf16 bf16x8 __attribute__((ext_vector_type(8)));
typedef float  f32x4  __attribute__((ext_vector_type(4)));
typedef unsigned short u16;

__device__ __forceinline__ u16 f2b(float f) {
    return __builtin_bit_cast(unsigned short, (__bf16)f);
}
__device__ __forceinline__ void gload16(void* lds, const void* g) {
    __builtin_amdgcn_global_load_lds(
        (const __attribute__((address_space(1))) void*)g,
        (__attribute__((address_space(3))) void*)lds, 16, 0, 0);
}
// tanh-approx GELU (err ~3e-4 << bf16 ulp)
__device__ __forceinline__ float gelu_f(float v) {
    float z = 0.7978845608f * (v + 0.044715f * v * v * v);
    float t = 1.0f - 2.0f / (1.0f + __expf(2.0f * z));
    return 0.5f * v * (1.0f + t);
}

// ---------------- init: cnt/rowmap/rowgate/out_main in ONE dispatch ---------
__global__ void init_k(int* __restrict__ cnt, int* __restrict__ rowmap,
                       float* __restrict__ rowgate, float* __restrict__ outm) {
    int tid = blockIdx.x * 256 + threadIdx.x;
    int nth = gridDim.x * 256;
    if (tid < E_EXP) cnt[tid] = 0;
    for (int i = tid; i < NROWS; i += nth) { rowmap[i] = -1; rowgate[i] = 0.f; }
    float4* o4 = (float4*)outm;
    for (int i = tid; i < (T_TOK * D_DIM) / 4; i += nth)
        o4[i] = float4{0.f, 0.f, 0.f, 0.f};
}

// ---------------- anchors: a_n = a / max(||a||, eps) ------------------------
__global__ void anchors_k(const float* __restrict__ anchors,
                          float* __restrict__ an, float* __restrict__ dout_an) {
    int tid = threadIdx.x;           // 512 threads = 8 waves, wave e = anchor e
    int lane = tid & 63, e = tid >> 6;
    const float4* ar = (const float4*)(anchors + e * D_DIM + lane * 8);
    float4 v0 = ar[0], v1 = ar[1];
    float ss = v0.x*v0.x + v0.y*v0.y + v0.z*v0.z + v0.w*v0.w
             + v1.x*v1.x + v1.y*v1.y + v1.z*v1.z + v1.w*v1.w;
#pragma unroll
    for (int off = 32; off >= 1; off >>= 1) ss += __shfl_xor(ss, off, 64);
    float inv = 1.0f / fmaxf(sqrtf(ss), 1e-8f);
    float o[8] = {v0.x*inv, v0.y*inv, v0.z*inv, v0.w*inv,
                  v1.x*inv, v1.y*inv, v1.z*inv, v1.w*inv};
#pragma unroll
    for (int i = 0; i < 8; ++i) {
        an[e * D_DIM + lane * 8 + i] = o[i];
        dout_an[e * D_DIM + lane * 8 + i] = o[i];
    }
}

// ---------------- routing: 4 threads per token ------------------------------
__global__ void routing_k(const float* __restrict__ x, const float* __restrict__ an,
                          float* __restrict__ dout_scores, float* __restrict__ dout_idx,
                          int* __restrict__ idxs, float* __restrict__ gates,
                          int* __restrict__ cnt) {
    __shared__ float anl[E_EXP * 544];   // [e][p*136 + i], i<128
    __shared__ int hist[E_EXP];
    int tid = threadIdx.x;
    if (tid < E_EXP) hist[tid] = 0;
    for (int i = tid; i < E_EXP * D_DIM; i += 256) {
        int e = i >> 9, d = i & 511;
        anl[e * 544 + (d >> 7) * 136 + (d & 127)] = an[i];
    }
    __syncthreads();

    int p = tid & 3;
    int tok = blockIdx.x * 64 + (tid >> 2);
    const float4* xr = (const float4*)(x + (size_t)tok * D_DIM + p * 128);
    const float* ab = &anl[p * 136];
    float dot[E_EXP] = {};
    float ss = 0.f;
    for (int c = 0; c < 32; ++c) {
        float4 xv = xr[c];
        ss += xv.x*xv.x + xv.y*xv.y + xv.z*xv.z + xv.w*xv.w;
#pragma unroll
        for (int e = 0; e < E_EXP; ++e) {
            float4 av = *(const float4*)&ab[e * 544 + c * 4];
            dot[e] += xv.x*av.x + xv.y*av.y + xv.z*av.z + xv.w*av.w;
        }
    }
#pragma unroll
    for (int off = 1; off <= 2; off <<= 1) {
        ss += __shfl_xor(ss, off, 64);
#pragma unroll
        for (int e = 0; e < E_EXP; ++e) dot[e] += __shfl_xor(dot[e], off, 64);
    }

    if (p == 0) {
        float inv = 1.0f / fmaxf(sqrtf(ss), 1e-8f);
        float s[E_EXP];
#pragma unroll
        for (int e = 0; e < E_EXP; ++e) s[e] = dot[e] * inv;
        int i0 = 0; float b0 = s[0];
#pragma unroll
        for (int e = 1; e < E_EXP; ++e) if (s[e] > b0) { b0 = s[e]; i0 = e; }
        int i1 = -1; float b1v = -1e30f;
#pragma unroll
        for (int e = 0; e < E_EXP; ++e)
            if (e != i0 && s[e] > b1v) { b1v = s[e]; i1 = e; }
        if (i1 < 0) { i1 = (i0 + 1) & 7; b1v = s[i1]; }   // NaN-safety
        float g0 = 1.0f / (1.0f + expf(b1v - b0));
        float g1 = 1.0f - g0;
#pragma unroll
        for (int e = 0; e < E_EXP; ++e) dout_scores[tok * E_EXP + e] = s[e];
        dout_idx[tok * 2 + 0] = (float)i0;
        dout_idx[tok * 2 + 1] = (float)i1;
        idxs[tok * 2 + 0] = i0; idxs[tok * 2 + 1] = i1;
        gates[tok * 2 + 0] = g0; gates[tok * 2 + 1] = g1;
        atomicAdd(&hist[i0], 1);
        atomicAdd(&hist[i1], 1);
    }
    __syncthreads();
    if (tid < E_EXP) atomicAdd(&cnt[tid], hist[tid]);
}

// ---------------- offsets (128-padded) + cursors ----------------------------
__global__ void offs_k(const int* __restrict__ cnt, int* __restrict__ offs,
                       int* __restrict__ cur) {
    if (threadIdx.x == 0 && blockIdx.x == 0) {
        int acc = 0;
        for (int e = 0; e < E_EXP; ++e) {
            offs[e] = acc; cur[e] = acc;
            acc += (cnt[e] + 127) & ~127;
        }
        offs[E_EXP] = acc;
    }
}

// ---------------- slot assignment (bounds-clamped) --------------------------
__global__ void assign_k(const int* __restrict__ idxs, const float* __restrict__ gates,
                         int* __restrict__ cur, int* __restrict__ rowmap,
                         float* __restrict__ rowgate) {
    int t = blockIdx.x * 256 + threadIdx.x;
    if (t >= T_TOK) return;
#pragma unroll
    for (int k = 0; k < 2; ++k) {
        int e = idxs[t * 2 + k];
        e = min(max(e, 0), E_EXP - 1);
        int r = atomicAdd(&cur[e], 1);
        if (r >= 0 && r < NROWS) {
            rowmap[r] = t;
            rowgate[r] = gates[t * 2 + k];
        }
    }
}

// ---------------- gather tokens -> bf16 rows (pad rows zeroed) --------------
__global__ void gather_k(const float* __restrict__ x, const int* __restrict__ rowmap,
                         u16* __restrict__ Xg) {
    int r = blockIdx.x;
    int t = rowmap[r];
    int c = threadIdx.x * 2;     // 256 threads x 2 = 512 elems
    ushort2 o;
    if (t < 0 || t >= T_TOK) { o.x = 0; o.y = 0; }
    else {
        float2 v = *(const float2*)(x + (size_t)t * D_DIM + c);
        o.x = f2b(v.x); o.y = f2b(v.y);
    }
    *(ushort2*)(Xg + (size_t)r * D_DIM + c) = o;
}

// ---------------- transpose+cast fp32 [Z][R][C] -> bf16 [Z][C][R] -----------
__global__ void transpose_cast_k(const float* __restrict__ in, u16* __restrict__ out,
                                 int R, int C) {
    size_t zoff = (size_t)blockIdx.z * R * C;
    in += zoff; out += zoff;
    __shared__ float t[64][65];
    int c0 = blockIdx.x * 64, r0 = blockIdx.y * 64;
    int tid = threadIdx.x;
    int cq = tid & 15, rb = tid >> 4;
#pragma unroll
    for (int pass = 0; pass < 4; ++pass) {
        int rr = rb + pass * 16;
        float4 v = *(const float4*)(in + (size_t)(r0 + rr) * C + c0 + cq * 4);
        t[rr][cq * 4 + 0] = v.x; t[rr][cq * 4 + 1] = v.y;
        t[rr][cq * 4 + 2] = v.z; t[rr][cq * 4 + 3] = v.w;
    }
    __syncthreads();
    int rg = tid & 15, cb = tid >> 4;
#pragma unroll
    for (int pass = 0; pass < 4; ++pass) {
        int c = cb + pass * 16;
        ushort4 o;
        o.x = f2b(t[rg * 4 + 0][c]); o.y = f2b(t[rg * 4 + 1][c]);
        o.z = f2b(t[rg * 4 + 2][c]); o.w = f2b(t[rg * 4 + 3][c]);
        *(ushort4*)(out + (size_t)(c0 + c) * R + r0 + rg * 4) = o;
    }
}

// ---------------- grouped GEMM core (linear LDS, XCD-swizzled 1D grid) ------
// MODE 0: Hg = bf16(gelu(Xg @ W1e^T + b1e))         (N=F, K=D), NT=16
// MODE 1: out[tok] += gate*(Hg @ W2e^T + [z0]b2e)   (N=D, K=F, split-K=2), NT=4
// 1D grid; tile = (L%8)*(total/8) + L/8  -> contiguous m-tile range per XCD.
template <int MODE>
__launch_bounds__(256, 4)
__global__ void gemm_k(const u16* __restrict__ A, int lda,
                       const u16* __restrict__ BtBase, int ldb,
                       u16* __restrict__ Hout, const float* __restrict__ b1,
                       float* __restrict__ outm, const float* __restrict__ b2,
                       const int* __restrict__ rowmap, const float* __restrict__ rowgate,
                       const int* __restrict__ offs, int kPer, int nT) {
    int L = blockIdx.x;
    int per = gridDim.x >> 3;
    int tile = (L & 7) * per + (L >> 3);
    int z = 0;
    if (MODE == 1) {                 // split-K 2: high half of tiles is z=1
        int half = gridDim.x >> 1;
        z = tile >= half; tile -= z * half;
    }
    int mtile = tile / nT;
    int n0 = (tile - mtile * nT) * 128;
    int row0 = mtile * 128;
    if (row0 >= offs[E_EXP]) return;
    int e = 0;
#pragma unroll
    for (int i = 1; i < E_EXP; ++i) if (row0 >= offs[i]) e = i;
    const u16* Bt = BtBase + (size_t)e * D_DIM * F_DIM;
    int k_begin = z * kPer;
    int k_end = k_begin + kPer;

    alignas(16) __shared__ u16 As[128 * 64];
    alignas(16) __shared__ u16 Bs[128 * 64];

    int tid = threadIdx.x;
    int lane = tid & 63;
    int wv = tid >> 6;
    int wm = wv & 1, wn = wv >> 1;
    int kq = lane >> 4;          // quad 0..3
    int l15 = lane & 15;

    // staging: slot = i*256 + tid; m = slot>>3; kc = slot&7 (linear)
    const u16* aSrc[4]; const u16* bSrc[4];
    u16* aDst[4]; u16* bDst[4];
#pragma unroll
    for (int i = 0; i < 4; ++i) {
        int slot = i * 256 + tid;
        int m = slot >> 3;
        int kc = slot & 7;
        aSrc[i] = A + (size_t)(row0 + m) * lda + kc * 8;
        bSrc[i] = Bt + (size_t)(n0 + m) * ldb + kc * 8;
        aDst[i] = As + slot * 8;
        bDst[i] = Bs + slot * 8;
    }

    f32x4 acc[4][4];
#pragma unroll
    for (int i = 0; i < 4; ++i)
#pragma unroll
        for (int j = 0; j < 4; ++j) acc[i][j] = f32x4{0.f, 0.f, 0.f, 0.f};

    for (int k0 = k_begin; k0 < k_end; k0 += 64) {
#pragma unroll
        for (int i = 0; i < 4; ++i) gload16(aDst[i], aSrc[i] + k0);
#pragma unroll
        for (int i = 0; i < 4; ++i) gload16(bDst[i], bSrc[i] + k0);
        asm volatile("s_waitcnt vmcnt(0)" ::: "memory");
        __syncthreads();
#pragma unroll
        for (int kk = 0; kk < 2; ++kk) {
            int kc = kk * 4 + kq;
            bf16x8 af[4], bfr[4];
#pragma unroll
            for (int i = 0; i < 4; ++i) {
                int rowA = wm * 64 + i * 16 + l15;
                af[i] = *(const bf16x8*)(As + rowA * 64 + kc * 8);
                int rowB = wn * 64 + i * 16 + l15;
                bfr[i] = *(const bf16x8*)(Bs + rowB * 64 + kc * 8);
            }
#pragma unroll
            for (int i = 0; i < 4; ++i)
#pragma unroll
                for (int j = 0; j < 4; ++j)
                    acc[i][j] = __builtin_amdgcn_mfma_f32_16x16x32_bf16(
                        af[i], bfr[j], acc[i][j], 0, 0, 0);
        }
        __syncthreads();
    }

    if constexpr (MODE == 0) {
        const float* b1e = b1 + (size_t)e * F_DIM;
#pragma unroll
        for (int i = 0; i < 4; ++i) {
            int gr = row0 + wm * 64 + i * 16 + kq * 4;
#pragma unroll
            for (int j = 0; j < 4; ++j) {
                int gc = n0 + wn * 64 + j * 16 + l15;
                float bb = b1e[gc];
#pragma unroll
                for (int r = 0; r < 4; ++r) {
                    float v = acc[i][j][r] + bb;
                    Hout[(size_t)(gr + r) * F_DIM + gc] = f2b(gelu_f(v));
                }
            }
        }
    } else {
        const float* b2e = b2 + (size_t)e * D_DIM;
        bool addBias = (k_begin == 0);
#pragma unroll
        for (int i = 0; i < 4; ++i) {
            int grb = row0 + wm * 64 + i * 16 + kq * 4;
#pragma unroll
            for (int r = 0; r < 4; ++r) {
                int tok = rowmap[grb + r];
                float g = rowgate[grb + r];
                if (tok >= 0 && tok < T_TOK) {
                    float* orow = outm + (size_t)tok * D_DIM;
#pragma unroll
                    for (int j = 0; j < 4; ++j) {
                        int gc = n0 + wn * 64 + j * 16 + l15;
                        float bb = addBias ? b2e[gc] : 0.f;
                        atomicAdd(orow + gc, g * (acc[i][j][r] + bb));
                    }
                }
            }
        }
    }
}

// ---------------- workspace layout (bytes) — total need ~81 MB --------------
#define OFF_AN      0u           // 16 KB fp32 a_n
#define OFF_CNT     0x10000u
#define OFF_OFFS    0x10100u
#define OFF_CUR     0x10200u
#define OFF_IDX     0x20000u     // int[T*2]
#define OFF_GATE    0x28000u     // float[T*2]
#define OFF_ROWMAP  0x30000u     // int[NROWS]
#define OFF_ROWGATE 0x40000u     // float[NROWS]
#define OFF_XG      0x900000u    // 9.44 MB u16[NROWS*D]  -> ends 0x1200000
#define OFF_W1T     0x1200000u   // 16.78 MB u16[E][F][D] -> ends 0x2200000
#define OFF_W2T     0x2200000u   // 16.78 MB u16[E][D][F] -> ends 0x3200000
#define OFF_HG      0x3200000u   // 37.75 MB u16[NROWS*F] -> ends 0x5600000

extern "C" void kernel_launch(void* const* d_in, const int* in_sizes, int n_in,
                              void* d_out, int out_size, void* d_ws, size_t ws_size,
                              hipStream_t stream) {
    const float* x       = (const float*)d_in[0];
    const float* anchors = (const float*)d_in[1];
    const float* W1      = (const float*)d_in[2];
    const float* b1      = (const float*)d_in[3];
    const float* W2      = (const float*)d_in[4];
    const float* b2      = (const float*)d_in[5];
    float* out = (float*)d_out;

    char* ws = (char*)d_ws;
    float* an      = (float*)(ws + OFF_AN);
    int*   cnt     = (int*)(ws + OFF_CNT);
    int*   offs    = (int*)(ws + OFF_OFFS);
    int*   cur     = (int*)(ws + OFF_CUR);
    int*   idxs    = (int*)(ws + OFF_IDX);
    float* gates   = (float*)(ws + OFF_GATE);
    int*   rowmap  = (int*)(ws + OFF_ROWMAP);
    float* rowgate = (float*)(ws + OFF_ROWGATE);
    u16*   Xg      = (u16*)(ws + OFF_XG);
    u16*   W1T     = (u16*)(ws + OFF_W1T);
    u16*   W2T     = (u16*)(ws + OFF_W2T);
    u16*   Hg      = (u16*)(ws + OFF_HG);

    // d_out sections (fp32 elements): out | a_n | scores | topk_idx
    float* out_main   = out;
    float* out_an     = out + (size_t)T_TOK * D_DIM;
    float* out_scores = out_an + E_EXP * D_DIM;
    float* out_idx    = out_scores + (size_t)T_TOK * E_EXP;

    init_k<<<512, 256, 0, stream>>>(cnt, rowmap, rowgate, out_main);
    anchors_k<<<1, 512, 0, stream>>>(anchors, an, out_an);
    routing_k<<<T_TOK / 64, 256, 0, stream>>>(x, an, out_scores, out_idx,
                                              idxs, gates, cnt);
    offs_k<<<1, 64, 0, stream>>>(cnt, offs, cur);
    assign_k<<<T_TOK / 256, 256, 0, stream>>>(idxs, gates, cur, rowmap, rowgate);
    gather_k<<<NROWS, 256, 0, stream>>>(x, rowmap, Xg);
    // W1 [E][D][F] -> W1T [E][F][D];  W2 [E][F][D] -> W2T [E][D][F]
    transpose_cast_k<<<dim3(F_DIM / 64, D_DIM / 64, E_EXP), 256, 0, stream>>>(
        W1, W1T, D_DIM, F_DIM);
    transpose_cast_k<<<dim3(D_DIM / 64, F_DIM / 64, E_EXP), 256, 0, stream>>>(
        W2, W2T, F_DIM, D_DIM);
    // gemm1: 16 n-tiles x 72 m-tiles = 1152 blocks (1D, XCD-swizzled)
    gemm_k<0><<<16 * MAXTILES, 256, 0, stream>>>(
        Xg, D_DIM, W1T, D_DIM, Hg, b1, nullptr, nullptr,
        rowmap, nullptr, offs, D_DIM, 16);
    // gemm2: 4 n-tiles x 72 m-tiles x splitK2 = 576 blocks (1D, XCD-swizzled)
    gemm_k<1><<<4 * MAXTILES * 2, 256, 0, stream>>>(
        Hg, F_DIM, W2T, F_DIM, nullptr, nullptr, out_main, b2,
        rowmap, rowgate, offs, F_DIM / 2, 4);
}

// Round 13
// 243.123 us; speedup vs baseline: 3.0511x; 1.1357x over previous
//
#include <hip/hip_runtime.h>
#include <cstdint>

// ---------------------------------------------------------------------------
// Round 13 vs round 12 (276.1 µs): dispatch-count attack. Summed kernel time
// ~155 µs vs 276 total => ~120 µs of inter-dispatch gaps over 10 dispatches.
// Fuse 10 -> 6: [init+anchors], routing, [offs+assign], [gather+T(W1)+T(W2)],
// gemm1, gemm2. GEMM cores identical to r12 (XCD swizzle kept, FETCH=ideal).
// ---------------------------------------------------------------------------

#define T_TOK 4096
#define D_DIM 512
#define F_DIM 2048
#define E_EXP 8
#define NROWS 9216      // 8192 assignments + 8*128 pad
#define MAXTILES 72     // NROWS / 128

typedef __bf16 bf16x8 __attribute__((ext_vector_type(8)));
typedef float  f32x4  __attribute__((ext_vector_type(4)));
typedef unsigned short u16;

__device__ __forceinline__ u16 f2b(float f) {
    return __builtin_bit_cast(unsigned short, (__bf16)f);
}
__device__ __forceinline__ void gload16(void* lds, const void* g) {
    __builtin_amdgcn_global_load_lds(
        (const __attribute__((address_space(1))) void*)g,
        (__attribute__((address_space(3))) void*)lds, 16, 0, 0);
}
// tanh-approx GELU (err ~3e-4 << bf16 ulp)
__device__ __forceinline__ float gelu_f(float v) {
    float z = 0.7978845608f * (v + 0.044715f * v * v * v);
    float t = 1.0f - 2.0f / (1.0f + __expf(2.0f * z));
    return 0.5f * v * (1.0f + t);
}

// ---------------- init (zeroing) + anchors in ONE dispatch ------------------
__global__ void init_k(int* __restrict__ cnt, int* __restrict__ rowmap,
                       float* __restrict__ rowgate, float* __restrict__ outm,
                       const float* __restrict__ anchors,
                       float* __restrict__ an, float* __restrict__ dout_an) {
    int tid = blockIdx.x * 256 + threadIdx.x;
    int nth = gridDim.x * 256;
    if (tid < E_EXP) cnt[tid] = 0;
    for (int i = tid; i < NROWS; i += nth) { rowmap[i] = -1; rowgate[i] = 0.f; }
    float4* o4 = (float4*)outm;
    for (int i = tid; i < (T_TOK * D_DIM) / 4; i += nth)
        o4[i] = float4{0.f, 0.f, 0.f, 0.f};
    // last block: anchor norms, 32 threads per anchor (8 anchors x 32 = 256)
    if (blockIdx.x == gridDim.x - 1) {
        int t = threadIdx.x;
        int e = t >> 5, l = t & 31;
        const float4* ar = (const float4*)(anchors + e * D_DIM + l * 16);
        float4 v0 = ar[0], v1 = ar[1], v2 = ar[2], v3 = ar[3];
        float ss = v0.x*v0.x + v0.y*v0.y + v0.z*v0.z + v0.w*v0.w
                 + v1.x*v1.x + v1.y*v1.y + v1.z*v1.z + v1.w*v1.w
                 + v2.x*v2.x + v2.y*v2.y + v2.z*v2.z + v2.w*v2.w
                 + v3.x*v3.x + v3.y*v3.y + v3.z*v3.z + v3.w*v3.w;
#pragma unroll
        for (int off = 16; off >= 1; off >>= 1) ss += __shfl_xor(ss, off, 32);
        float inv = 1.0f / fmaxf(sqrtf(ss), 1e-8f);
        float o[16] = {v0.x*inv, v0.y*inv, v0.z*inv, v0.w*inv,
                       v1.x*inv, v1.y*inv, v1.z*inv, v1.w*inv,
                       v2.x*inv, v2.y*inv, v2.z*inv, v2.w*inv,
                       v3.x*inv, v3.y*inv, v3.z*inv, v3.w*inv};
#pragma unroll
        for (int i = 0; i < 16; ++i) {
            an[e * D_DIM + l * 16 + i] = o[i];
            dout_an[e * D_DIM + l * 16 + i] = o[i];
        }
    }
}

// ---------------- routing: 4 threads per token ------------------------------
__global__ void routing_k(const float* __restrict__ x, const float* __restrict__ an,
                          float* __restrict__ dout_scores, float* __restrict__ dout_idx,
                          int* __restrict__ idxs, float* __restrict__ gates,
                          int* __restrict__ cnt) {
    __shared__ float anl[E_EXP * 544];   // [e][p*136 + i], i<128
    __shared__ int hist[E_EXP];
    int tid = threadIdx.x;
    if (tid < E_EXP) hist[tid] = 0;
    for (int i = tid; i < E_EXP * D_DIM; i += 256) {
        int e = i >> 9, d = i & 511;
        anl[e * 544 + (d >> 7) * 136 + (d & 127)] = an[i];
    }
    __syncthreads();

    int p = tid & 3;
    int tok = blockIdx.x * 64 + (tid >> 2);
    const float4* xr = (const float4*)(x + (size_t)tok * D_DIM + p * 128);
    const float* ab = &anl[p * 136];
    float dot[E_EXP] = {};
    float ss = 0.f;
    for (int c = 0; c < 32; ++c) {
        float4 xv = xr[c];
        ss += xv.x*xv.x + xv.y*xv.y + xv.z*xv.z + xv.w*xv.w;
#pragma unroll
        for (int e = 0; e < E_EXP; ++e) {
            float4 av = *(const float4*)&ab[e * 544 + c * 4];
            dot[e] += xv.x*av.x + xv.y*av.y + xv.z*av.z + xv.w*av.w;
        }
    }
#pragma unroll
    for (int off = 1; off <= 2; off <<= 1) {
        ss += __shfl_xor(ss, off, 64);
#pragma unroll
        for (int e = 0; e < E_EXP; ++e) dot[e] += __shfl_xor(dot[e], off, 64);
    }

    if (p == 0) {
        float inv = 1.0f / fmaxf(sqrtf(ss), 1e-8f);
        float s[E_EXP];
#pragma unroll
        for (int e = 0; e < E_EXP; ++e) s[e] = dot[e] * inv;
        int i0 = 0; float b0 = s[0];
#pragma unroll
        for (int e = 1; e < E_EXP; ++e) if (s[e] > b0) { b0 = s[e]; i0 = e; }
        int i1 = -1; float b1v = -1e30f;
#pragma unroll
        for (int e = 0; e < E_EXP; ++e)
            if (e != i0 && s[e] > b1v) { b1v = s[e]; i1 = e; }
        if (i1 < 0) { i1 = (i0 + 1) & 7; b1v = s[i1]; }   // NaN-safety
        float g0 = 1.0f / (1.0f + expf(b1v - b0));
        float g1 = 1.0f - g0;
#pragma unroll
        for (int e = 0; e < E_EXP; ++e) dout_scores[tok * E_EXP + e] = s[e];
        dout_idx[tok * 2 + 0] = (float)i0;
        dout_idx[tok * 2 + 1] = (float)i1;
        idxs[tok * 2 + 0] = i0; idxs[tok * 2 + 1] = i1;
        gates[tok * 2 + 0] = g0; gates[tok * 2 + 1] = g1;
        atomicAdd(&hist[i0], 1);
        atomicAdd(&hist[i1], 1);
    }
    __syncthreads();
    if (tid < E_EXP) atomicAdd(&cnt[tid], hist[tid]);
}

// ---------------- offsets + slot assignment, ONE block (LDS cursors) --------
__global__ void assign_k(const int* __restrict__ cnt, int* __restrict__ offs,
                         const int* __restrict__ idxs, const float* __restrict__ gates,
                         int* __restrict__ rowmap, float* __restrict__ rowgate) {
    __shared__ int scur[E_EXP];
    int tid = threadIdx.x;
    if (tid == 0) {
        int acc = 0;
        for (int e = 0; e < E_EXP; ++e) {
            offs[e] = acc; scur[e] = acc;
            acc += (cnt[e] + 127) & ~127;
        }
        offs[E_EXP] = acc;
    }
    __syncthreads();
    for (int t = tid; t < T_TOK; t += 1024) {
#pragma unroll
        for (int k = 0; k < 2; ++k) {
            int e = idxs[t * 2 + k];
            e = min(max(e, 0), E_EXP - 1);
            int r = atomicAdd(&scur[e], 1);
            if (r >= 0 && r < NROWS) {
                rowmap[r] = t;
                rowgate[r] = gates[t * 2 + k];
            }
        }
    }
}

// ---------------- prep: gather + transpose(W1) + transpose(W2), ONE dispatch
__device__ __forceinline__ void tbody(const float* __restrict__ in,
                                      u16* __restrict__ out, int R, int C,
                                      int c0, int r0, int tid,
                                      float (*t)[65]) {
    int cq = tid & 15, rb = tid >> 4;
#pragma unroll
    for (int pass = 0; pass < 4; ++pass) {
        int rr = rb + pass * 16;
        float4 v = *(const float4*)(in + (size_t)(r0 + rr) * C + c0 + cq * 4);
        t[rr][cq * 4 + 0] = v.x; t[rr][cq * 4 + 1] = v.y;
        t[rr][cq * 4 + 2] = v.z; t[rr][cq * 4 + 3] = v.w;
    }
    __syncthreads();
    int rg = tid & 15, cb = tid >> 4;
#pragma unroll
    for (int pass = 0; pass < 4; ++pass) {
        int c = cb + pass * 16;
        ushort4 o;
        o.x = f2b(t[rg * 4 + 0][c]); o.y = f2b(t[rg * 4 + 1][c]);
        o.z = f2b(t[rg * 4 + 2][c]); o.w = f2b(t[rg * 4 + 3][c]);
        *(ushort4*)(out + (size_t)(c0 + c) * R + r0 + rg * 4) = o;
    }
}

#define T1_BASE NROWS                    // 9216
#define T2_BASE (NROWS + 2048)           // 11264
#define PREP_BLOCKS (NROWS + 4096)       // 13312

__global__ void prep_k(const float* __restrict__ x, const int* __restrict__ rowmap,
                       u16* __restrict__ Xg,
                       const float* __restrict__ W1, u16* __restrict__ W1T,
                       const float* __restrict__ W2, u16* __restrict__ W2T) {
    __shared__ float tsh[64][65];
    int b = blockIdx.x;
    int tid = threadIdx.x;
    if (b < T1_BASE) {                      // gather row b
        int t = rowmap[b];
        int c = tid * 2;
        ushort2 o;
        if (t < 0 || t >= T_TOK) { o.x = 0; o.y = 0; }
        else {
            float2 v = *(const float2*)(x + (size_t)t * D_DIM + c);
            o.x = f2b(v.x); o.y = f2b(v.y);
        }
        *(ushort2*)(Xg + (size_t)b * D_DIM + c) = o;
    } else if (b < T2_BASE) {               // W1 [E][512][2048] -> [E][2048][512]
        int tt = b - T1_BASE;
        int bx = tt & 31, by = (tt >> 5) & 7, bz = tt >> 8;
        size_t zoff = (size_t)bz * D_DIM * F_DIM;
        tbody(W1 + zoff, W1T + zoff, D_DIM, F_DIM, bx * 64, by * 64, tid, tsh);
    } else {                                // W2 [E][2048][512] -> [E][512][2048]
        int tt = b - T2_BASE;
        int bx = tt & 7, by = (tt >> 3) & 31, bz = tt >> 8;
        size_t zoff = (size_t)bz * D_DIM * F_DIM;
        tbody(W2 + zoff, W2T + zoff, F_DIM, D_DIM, bx * 64, by * 64, tid, tsh);
    }
}

// ---------------- grouped GEMM core (identical to round 12) -----------------
// MODE 0: Hg = bf16(gelu(Xg @ W1e^T + b1e))         (N=F, K=D), NT=16
// MODE 1: out[tok] += gate*(Hg @ W2e^T + [z0]b2e)   (N=D, K=F, split-K=2), NT=4
// 1D grid; tile = (L%8)*(total/8) + L/8  -> contiguous m-tile range per XCD.
template <int MODE>
__launch_bounds__(256, 4)
__global__ void gemm_k(const u16* __restrict__ A, int lda,
                       const u16* __restrict__ BtBase, int ldb,
                       u16* __restrict__ Hout, const float* __restrict__ b1,
                       float* __restrict__ outm, const float* __restrict__ b2,
                       const int* __restrict__ rowmap, const float* __restrict__ rowgate,
                       const int* __restrict__ offs, int kPer, int nT) {
    int L = blockIdx.x;
    int per = gridDim.x >> 3;
    int tile = (L & 7) * per + (L >> 3);
    int z = 0;
    if (MODE == 1) {                 // split-K 2: high half of tiles is z=1
        int half = gridDim.x >> 1;
        z = tile >= half; tile -= z * half;
    }
    int mtile = tile / nT;
    int n0 = (tile - mtile * nT) * 128;
    int row0 = mtile * 128;
    if (row0 >= offs[E_EXP]) return;
    int e = 0;
#pragma unroll
    for (int i = 1; i < E_EXP; ++i) if (row0 >= offs[i]) e = i;
    const u16* Bt = BtBase + (size_t)e * D_DIM * F_DIM;
    int k_begin = z * kPer;
    int k_end = k_begin + kPer;

    alignas(16) __shared__ u16 As[128 * 64];
    alignas(16) __shared__ u16 Bs[128 * 64];

    int tid = threadIdx.x;
    int lane = tid & 63;
    int wv = tid >> 6;
    int wm = wv & 1, wn = wv >> 1;
    int kq = lane >> 4;          // quad 0..3
    int l15 = lane & 15;

    // staging: slot = i*256 + tid; m = slot>>3; kc = slot&7 (linear)
    const u16* aSrc[4]; const u16* bSrc[4];
    u16* aDst[4]; u16* bDst[4];
#pragma unroll
    for (int i = 0; i < 4; ++i) {
        int slot = i * 256 + tid;
        int m = slot >> 3;
        int kc = slot & 7;
        aSrc[i] = A + (size_t)(row0 + m) * lda + kc * 8;
        bSrc[i] = Bt + (size_t)(n0 + m) * ldb + kc * 8;
        aDst[i] = As + slot * 8;
        bDst[i] = Bs + slot * 8;
    }

    f32x4 acc[4][4];
#pragma unroll
    for (int i = 0; i < 4; ++i)
#pragma unroll
        for (int j = 0; j < 4; ++j) acc[i][j] = f32x4{0.f, 0.f, 0.f, 0.f};

    for (int k0 = k_begin; k0 < k_end; k0 += 64) {
#pragma unroll
        for (int i = 0; i < 4; ++i) gload16(aDst[i], aSrc[i] + k0);
#pragma unroll
        for (int i = 0; i < 4; ++i) gload16(bDst[i], bSrc[i] + k0);
        asm volatile("s_waitcnt vmcnt(0)" ::: "memory");
        __syncthreads();
#pragma unroll
        for (int kk = 0; kk < 2; ++kk) {
            int kc = kk * 4 + kq;
            bf16x8 af[4], bfr[4];
#pragma unroll
            for (int i = 0; i < 4; ++i) {
                int rowA = wm * 64 + i * 16 + l15;
                af[i] = *(const bf16x8*)(As + rowA * 64 + kc * 8);
                int rowB = wn * 64 + i * 16 + l15;
                bfr[i] = *(const bf16x8*)(Bs + rowB * 64 + kc * 8);
            }
#pragma unroll
            for (int i = 0; i < 4; ++i)
#pragma unroll
                for (int j = 0; j < 4; ++j)
                    acc[i][j] = __builtin_amdgcn_mfma_f32_16x16x32_bf16(
                        af[i], bfr[j], acc[i][j], 0, 0, 0);
        }
        __syncthreads();
    }

    if constexpr (MODE == 0) {
        const float* b1e = b1 + (size_t)e * F_DIM;
#pragma unroll
        for (int i = 0; i < 4; ++i) {
            int gr = row0 + wm * 64 + i * 16 + kq * 4;
#pragma unroll
            for (int j = 0; j < 4; ++j) {
                int gc = n0 + wn * 64 + j * 16 + l15;
                float bb = b1e[gc];
#pragma unroll
                for (int r = 0; r < 4; ++r) {
                    float v = acc[i][j][r] + bb;
                    Hout[(size_t)(gr + r) * F_DIM + gc] = f2b(gelu_f(v));
                }
            }
        }
    } else {
        const float* b2e = b2 + (size_t)e * D_DIM;
        bool addBias = (k_begin == 0);
#pragma unroll
        for (int i = 0; i < 4; ++i) {
            int grb = row0 + wm * 64 + i * 16 + kq * 4;
#pragma unroll
            for (int r = 0; r < 4; ++r) {
                int tok = rowmap[grb + r];
                float g = rowgate[grb + r];
                if (tok >= 0 && tok < T_TOK) {
                    float* orow = outm + (size_t)tok * D_DIM;
#pragma unroll
                    for (int j = 0; j < 4; ++j) {
                        int gc = n0 + wn * 64 + j * 16 + l15;
                        float bb = addBias ? b2e[gc] : 0.f;
                        atomicAdd(orow + gc, g * (acc[i][j][r] + bb));
                    }
                }
            }
        }
    }
}

// ---------------- workspace layout (bytes) — total need ~81 MB --------------
#define OFF_AN      0u           // 16 KB fp32 a_n
#define OFF_CNT     0x10000u
#define OFF_OFFS    0x10100u
#define OFF_IDX     0x20000u     // int[T*2]
#define OFF_GATE    0x28000u     // float[T*2]
#define OFF_ROWMAP  0x30000u     // int[NROWS]
#define OFF_ROWGATE 0x40000u     // float[NROWS]
#define OFF_XG      0x900000u    // 9.44 MB u16[NROWS*D]  -> ends 0x1200000
#define OFF_W1T     0x1200000u   // 16.78 MB u16[E][F][D] -> ends 0x2200000
#define OFF_W2T     0x2200000u   // 16.78 MB u16[E][D][F] -> ends 0x3200000
#define OFF_HG      0x3200000u   // 37.75 MB u16[NROWS*F] -> ends 0x5600000

extern "C" void kernel_launch(void* const* d_in, const int* in_sizes, int n_in,
                              void* d_out, int out_size, void* d_ws, size_t ws_size,
                              hipStream_t stream) {
    const float* x       = (const float*)d_in[0];
    const float* anchors = (const float*)d_in[1];
    const float* W1      = (const float*)d_in[2];
    const float* b1      = (const float*)d_in[3];
    const float* W2      = (const float*)d_in[4];
    const float* b2      = (const float*)d_in[5];
    float* out = (float*)d_out;

    char* ws = (char*)d_ws;
    float* an      = (float*)(ws + OFF_AN);
    int*   cnt     = (int*)(ws + OFF_CNT);
    int*   offs    = (int*)(ws + OFF_OFFS);
    int*   idxs    = (int*)(ws + OFF_IDX);
    float* gates   = (float*)(ws + OFF_GATE);
    int*   rowmap  = (int*)(ws + OFF_ROWMAP);
    float* rowgate = (float*)(ws + OFF_ROWGATE);
    u16*   Xg      = (u16*)(ws + OFF_XG);
    u16*   W1T     = (u16*)(ws + OFF_W1T);
    u16*   W2T     = (u16*)(ws + OFF_W2T);
    u16*   Hg      = (u16*)(ws + OFF_HG);

    // d_out sections (fp32 elements): out | a_n | scores | topk_idx
    float* out_main   = out;
    float* out_an     = out + (size_t)T_TOK * D_DIM;
    float* out_scores = out_an + E_EXP * D_DIM;
    float* out_idx    = out_scores + (size_t)T_TOK * E_EXP;

    init_k<<<512, 256, 0, stream>>>(cnt, rowmap, rowgate, out_main,
                                    anchors, an, out_an);
    routing_k<<<T_TOK / 64, 256, 0, stream>>>(x, an, out_scores, out_idx,
                                              idxs, gates, cnt);
    assign_k<<<1, 1024, 0, stream>>>(cnt, offs, idxs, gates, rowmap, rowgate);
    prep_k<<<PREP_BLOCKS, 256, 0, stream>>>(x, rowmap, Xg, W1, W1T, W2, W2T);
    // gemm1: 16 n-tiles x 72 m-tiles = 1152 blocks (1D, XCD-swizzled)
    gemm_k<0><<<16 * MAXTILES, 256, 0, stream>>>(
        Xg, D_DIM, W1T, D_DIM, Hg, b1, nullptr, nullptr,
        rowmap, nullptr, offs, D_DIM, 16);
    // gemm2: 4 n-tiles x 72 m-tiles x splitK2 = 576 blocks (1D, XCD-swizzled)
    gemm_k<1><<<4 * MAXTILES * 2, 256, 0, stream>>>(
        Hg, F_DIM, W2T, F_DIM, nullptr, nullptr, out_main, b2,
        rowmap, rowgate, offs, F_DIM / 2, 4);
}